// Round 1
// baseline (295.312 us; speedup 1.0000x reference)
//
#include <hip/hip_runtime.h>
#include <hip/hip_bf16.h>

// TransformerLayer on MI355X (gfx950). Round 0: correct full pipeline,
// bf16 MFMA (16x16x32) for all matmuls, fp32 accumulate/epilogues.
//
// Shapes: B=2 S=2048 Dh=256 H=8 HID=1024; BS=4096 rows; E=H*Dh=2048.
// Outputs: out (4096*256 f32) then attn_weights (16*2048*2048 f32).

typedef __bf16 bf16_t;
typedef __bf16 bf16x8 __attribute__((ext_vector_type(8)));
typedef __bf16 bf16x4 __attribute__((ext_vector_type(4)));
typedef float  f32x4  __attribute__((ext_vector_type(4)));

#define DEV __device__ __forceinline__

DEV f32x4 mfma16(bf16x8 a, bf16x8 b, f32x4 c) {
  return __builtin_amdgcn_mfma_f32_16x16x32_bf16(a, b, c, 0, 0, 0);
}

// async global->LDS, 16B per lane; lds base must be wave-uniform (HW adds lane*16)
DEV void gload16(const void* g, void* l) {
  __builtin_amdgcn_global_load_lds(
      (const __attribute__((address_space(1))) unsigned int*)g,
      (__attribute__((address_space(3))) unsigned int*)l, 16, 0, 0);
}

// ---------------- weight fp32 -> bf16 ----------------
__global__ void cvt_w(const float* __restrict__ s, bf16_t* __restrict__ d, int n4) {
  int i = blockIdx.x * blockDim.x + threadIdx.x;
  int st = gridDim.x * blockDim.x;
  for (int j = i; j < n4; j += st) {
    float4 v = ((const float4*)s)[j];
    bf16x4 o = { (bf16_t)v.x, (bf16_t)v.y, (bf16_t)v.z, (bf16_t)v.w };
    ((bf16x4*)d)[j] = o;
  }
}

// ---------------- LayerNorm over 256, 1 wave per row ----------------
__global__ __launch_bounds__(256) void ln_k(const float* __restrict__ x,
    const float* __restrict__ g, const float* __restrict__ bta,
    float* __restrict__ of, bf16_t* __restrict__ ob) {
  int row = blockIdx.x * 4 + (threadIdx.x >> 6);
  int l = threadIdx.x & 63;
  const float4 v = *(const float4*)(x + (size_t)row * 256 + l * 4);
  float s  = v.x + v.y + v.z + v.w;
  float s2 = v.x*v.x + v.y*v.y + v.z*v.z + v.w*v.w;
#pragma unroll
  for (int o = 1; o < 64; o <<= 1) { s += __shfl_xor(s, o, 64); s2 += __shfl_xor(s2, o, 64); }
  float m   = s * (1.f/256.f);
  float var = s2 * (1.f/256.f) - m * m;
  float rs  = rsqrtf(var + 1e-9f);
  const float4 gv = *(const float4*)(g   + l * 4);
  const float4 bv = *(const float4*)(bta + l * 4);
  float4 y;
  y.x = (v.x - m) * rs * gv.x + bv.x;
  y.y = (v.y - m) * rs * gv.y + bv.y;
  y.z = (v.z - m) * rs * gv.z + bv.z;
  y.w = (v.w - m) * rs * gv.w + bv.w;
  if (of) *(float4*)(of + (size_t)row * 256 + l * 4) = y;
  bf16x4 yb = { (bf16_t)y.x, (bf16_t)y.y, (bf16_t)y.z, (bf16_t)y.w };
  *(bf16x4*)(ob + (size_t)row * 256 + l * 4) = yb;
}

// ---------------- generic C = A(M,K) * W(N,K)^T + bias, 128x128 tile ----------------
enum { M_QKV = 0, M_DENSE = 1, M_FC1 = 2, M_FC2 = 3 };

template<int MODE>
__global__ __launch_bounds__(256, 2) void gemm_bt(
    const bf16_t* __restrict__ A, const bf16_t* __restrict__ W,
    const float* __restrict__ bias, int K, int N,
    void* __restrict__ out, const float* __restrict__ res) {
  __shared__ bf16_t As[128 * 32];
  __shared__ bf16_t Bs[128 * 32];
  int tid = threadIdx.x;
  int w = tid >> 6, l = tid & 63, l15 = l & 15, lhi = l >> 4;
  int row0 = blockIdx.y * 128, col0 = blockIdx.x * 128;
  int wr = (w >> 1) * 64, wc = (w & 1) * 64;
  f32x4 acc[4][4] = {};

  for (int k0 = 0; k0 < K; k0 += 32) {
    __syncthreads();
#pragma unroll
    for (int j = 0; j < 2; ++j) {
      int idx = (j * 256 + tid) * 8;         // element index in 128x32 tile
      int r = idx >> 5, c = idx & 31;
      gload16(A + (size_t)(row0 + r) * K + k0 + c, (char*)As + j * 4096 + w * 1024);
      gload16(W + (size_t)(col0 + r) * K + k0 + c, (char*)Bs + j * 4096 + w * 1024);
    }
    __syncthreads();
    bf16x8 af[4], bfr[4];
#pragma unroll
    for (int m = 0; m < 4; ++m)
      af[m] = *(const bf16x8*)(As + (wr + 16 * m + l15) * 32 + lhi * 8);
#pragma unroll
    for (int n = 0; n < 4; ++n)
      bfr[n] = *(const bf16x8*)(Bs + (wc + 16 * n + l15) * 32 + lhi * 8);
#pragma unroll
    for (int m = 0; m < 4; ++m)
#pragma unroll
      for (int n = 0; n < 4; ++n)
        acc[m][n] = mfma16(af[m], bfr[n], acc[m][n]);
  }

#pragma unroll
  for (int m = 0; m < 4; ++m) {
#pragma unroll
    for (int n = 0; n < 4; ++n) {
#pragma unroll
      for (int j = 0; j < 4; ++j) {
        int row = row0 + wr + 16 * m + lhi * 4 + j;
        int col = col0 + wc + 16 * n + l15;
        float v = acc[m][n][j] + bias[col];
        if (MODE == M_QKV) {
          // out bf16 (B,H,S,Dh): b=row>>11, s=row&2047, h=col>>8, d=col&255
          ((bf16_t*)out)[((size_t)((row >> 11) * 8 + (col >> 8)) * 2048 + (row & 2047)) * 256 + (col & 255)] = (bf16_t)v;
        } else if (MODE == M_DENSE) {
          float x1 = res[(size_t)row * 256 + col] + v;   // res = xn (f32)
          ((float*)out)[(size_t)row * 256 + col] = x1;
        } else if (MODE == M_FC1) {
          float t = v;
          float ge = 0.5f * t * (1.f + tanhf(0.7978845608f * t * (1.f + 0.044715f * t * t)));
          ((bf16_t*)out)[(size_t)row * (size_t)N + col] = (bf16_t)ge;
        } else { // M_FC2
          ((float*)out)[(size_t)row * 256 + col] = v + res[(size_t)row * 256 + col];
        }
      }
    }
  }
}

// ---------------- V (B,H,S,Dh) -> V^T (B,H,Dh,S) ----------------
__global__ __launch_bounds__(256) void vtrans(const bf16_t* __restrict__ v, bf16_t* __restrict__ vt) {
  __shared__ bf16_t t[64 * 72];
  int bh = blockIdx.z;
  int s0 = blockIdx.x * 64, d0 = blockIdx.y * 64;
  int tid = threadIdx.x;
#pragma unroll
  for (int j = 0; j < 2; ++j) {
    int cj = j * 256 + tid;
    int r = cj >> 3, c = (cj & 7) * 8;
    *(bf16x8*)(t + r * 72 + c) = *(const bf16x8*)(v + ((size_t)bh * 2048 + s0 + r) * 256 + d0 + c);
  }
  __syncthreads();
#pragma unroll
  for (int j = 0; j < 2; ++j) {
    int cj = j * 256 + tid;
    int rd = cj >> 3, cs = (cj & 7) * 8;
    bf16x8 o;
#pragma unroll
    for (int i = 0; i < 8; ++i) o[i] = t[(cs + i) * 72 + rd];
    *(bf16x8*)(vt + ((size_t)bh * 256 + d0 + rd) * 2048 + s0 + cs) = o;
  }
}

// ---------------- fused causal attention, Q-tile=64, K-tile=64 ----------------
// grid 512: bh = bx&15, qt = 31 - (bx>>4) (longest blocks dispatch first)
__global__ __launch_bounds__(256, 2) void attn_k(
    const bf16_t* __restrict__ qg, const bf16_t* __restrict__ kg,
    const bf16_t* __restrict__ vt, float* __restrict__ pout,
    bf16_t* __restrict__ ctxo) {
  __shared__ bf16_t Ksh[64 * 256];   // 32KB, XOR-swizzled rows (512B)
  __shared__ bf16_t Vsh[256 * 64];   // 32KB, V^T tile, XOR-swizzled rows (128B)
  __shared__ bf16_t Psh[64 * 64];    // 8KB,  XOR-swizzled rows (128B)
  int bx = blockIdx.x;
  int bh = bx & 15, qt = 31 - (bx >> 4);
  int tid = threadIdx.x, w = tid >> 6, l = tid & 63;
  int l15 = l & 15, lhi = l >> 4, l7 = l & 7;
  const bf16_t* Q   = qg + (size_t)bh * 2048 * 256;
  const bf16_t* Kg2 = kg + (size_t)bh * 2048 * 256;
  const bf16_t* Vt  = vt + (size_t)bh * 256 * 2048;
  int qbase = qt * 64;

  // Q fragments in registers: wave w owns q-rows [qbase+w*16, +16)
  bf16x8 qf[8];
#pragma unroll
  for (int ks = 0; ks < 8; ++ks)
    qf[ks] = *(const bf16x8*)(Q + (size_t)(qbase + w * 16 + l15) * 256 + ks * 32 + lhi * 8);

  // ---- pass A: rowsum of exp ----
  float sums[4] = {0.f, 0.f, 0.f, 0.f};
  for (int kt = 0; kt <= qt; ++kt) {
    __syncthreads();
#pragma unroll
    for (int j = 0; j < 8; ++j) {
      int p = (j * 256 + tid) * 16;
      int r = p >> 9;
      int co = (p & 511) ^ ((r & 7) << 4);
      gload16(Kg2 + (size_t)(kt * 64 + r) * 256 + (co >> 1), (char*)Ksh + j * 4096 + w * 1024);
    }
    __syncthreads();
    f32x4 acc[4] = {};
#pragma unroll
    for (int ks = 0; ks < 8; ++ks) {
#pragma unroll
      for (int n = 0; n < 4; ++n) {
        bf16x8 kb = *(const bf16x8*)((const char*)Ksh + (16 * n + l15) * 512 + ((ks * 64 + lhi * 16) ^ (l7 << 4)));
        acc[n] = mfma16(qf[ks], kb, acc[n]);
      }
    }
#pragma unroll
    for (int n = 0; n < 4; ++n)
#pragma unroll
      for (int j = 0; j < 4; ++j) {
        int kc = kt * 64 + 16 * n + l15;
        int qr = qbase + w * 16 + lhi * 4 + j;
        sums[j] += (kc <= qr) ? __expf(acc[n][j] * 0.0625f) : 0.f;
      }
  }
#pragma unroll
  for (int j = 0; j < 4; ++j) {
#pragma unroll
    for (int o = 1; o < 16; o <<= 1) sums[j] += __shfl_xor(sums[j], o, 64);
    sums[j] = 1.f / sums[j];
  }

  // ---- pass B: P writes + PV ----
  f32x4 ctx[16] = {};
  for (int kt = 0; kt <= qt; ++kt) {
    __syncthreads();
#pragma unroll
    for (int j = 0; j < 8; ++j) {
      int p = (j * 256 + tid) * 16;
      { int r = p >> 9; int co = (p & 511) ^ ((r & 7) << 4);
        gload16(Kg2 + (size_t)(kt * 64 + r) * 256 + (co >> 1), (char*)Ksh + j * 4096 + w * 1024); }
      { int r = p >> 7; int co = (p & 127) ^ ((r & 7) << 4);
        gload16(Vt + (size_t)r * 2048 + kt * 64 + (co >> 1), (char*)Vsh + j * 4096 + w * 1024); }
    }
    __syncthreads();
    f32x4 acc[4] = {};
#pragma unroll
    for (int ks = 0; ks < 8; ++ks) {
#pragma unroll
      for (int n = 0; n < 4; ++n) {
        bf16x8 kb = *(const bf16x8*)((const char*)Ksh + (16 * n + l15) * 512 + ((ks * 64 + lhi * 16) ^ (l7 << 4)));
        acc[n] = mfma16(qf[ks], kb, acc[n]);
      }
    }
#pragma unroll
    for (int n = 0; n < 4; ++n) {
#pragma unroll
      for (int j = 0; j < 4; ++j) {
        int kc = kt * 64 + 16 * n + l15;
        int qr = qbase + w * 16 + lhi * 4 + j;
        float e = (kc <= qr) ? __expf(acc[n][j] * 0.0625f) * sums[j] : 0.f;
        pout[((size_t)bh * 2048 + qr) * 2048 + kc] = e;
        int prow = w * 16 + lhi * 4 + j;
        int pcb = (16 * n + l15) * 2;
        *(bf16_t*)((char*)Psh + prow * 128 + (pcb ^ ((prow & 7) << 4))) = (bf16_t)e;
      }
    }
    __syncthreads();
#pragma unroll
    for (int k2 = 0; k2 < 2; ++k2) {
      bf16x8 pa = *(const bf16x8*)((const char*)Psh + (w * 16 + l15) * 128 + ((k2 * 64 + lhi * 16) ^ (l7 << 4)));
#pragma unroll
      for (int n = 0; n < 16; ++n) {
        bf16x8 vb = *(const bf16x8*)((const char*)Vsh + (16 * n + l15) * 128 + ((k2 * 64 + lhi * 16) ^ (l7 << 4)));
        ctx[n] = mfma16(pa, vb, ctx[n]);
      }
    }
  }

  // ctx write: (b, s, h*256+d) bf16
  int b = bh >> 3, h = bh & 7;
#pragma unroll
  for (int n = 0; n < 16; ++n)
#pragma unroll
    for (int j = 0; j < 4; ++j) {
      int qr = qbase + w * 16 + lhi * 4 + j;
      ctxo[((size_t)b * 2048 + qr) * 2048 + h * 256 + 16 * n + l15] = (bf16_t)ctx[n][j];
    }

  // zero-fill masked upper region
  int zs = qbase + 64;
  for (int r = 0; r < 64; ++r) {
    size_t base = ((size_t)bh * 2048 + qbase + r) * 2048;
    for (int c = zs + tid * 4; c < 2048; c += 1024) {
      *(float4*)(pout + base + c) = make_float4(0.f, 0.f, 0.f, 0.f);
    }
  }
}

// ---------------- host launch ----------------
extern "C" void kernel_launch(void* const* d_in, const int* in_sizes, int n_in,
                              void* d_out, int out_size, void* d_ws, size_t ws_size,
                              hipStream_t stream) {
  const float* x     = (const float*)d_in[0];
  const float* ln1g  = (const float*)d_in[2];
  const float* ln1b  = (const float*)d_in[3];
  const float* wq_w  = (const float*)d_in[4];
  const float* wq_b  = (const float*)d_in[5];
  const float* wk_w  = (const float*)d_in[6];
  const float* wk_b  = (const float*)d_in[7];
  const float* wv_w  = (const float*)d_in[8];
  const float* wv_b  = (const float*)d_in[9];
  const float* dw    = (const float*)d_in[10];
  const float* db    = (const float*)d_in[11];
  const float* ln2g  = (const float*)d_in[12];
  const float* ln2b  = (const float*)d_in[13];
  const float* f1w   = (const float*)d_in[14];
  const float* f1b   = (const float*)d_in[15];
  const float* f2w   = (const float*)d_in[16];
  const float* f2b   = (const float*)d_in[17];

  char* ws = (char*)d_ws;
  const size_t MB = 1u << 20;
  float*  xn_f = (float*) (ws + 0 * MB);    // 4MB
  bf16_t* xn_b = (bf16_t*)(ws + 4 * MB);    // 2MB
  bf16_t* q_b  = (bf16_t*)(ws + 6 * MB);    // 16MB
  bf16_t* k_b  = (bf16_t*)(ws + 22 * MB);   // 16MB
  bf16_t* v_b  = (bf16_t*)(ws + 38 * MB);   // 16MB (reused as ctx after vtrans)
  bf16_t* vt_b = (bf16_t*)(ws + 54 * MB);   // 16MB
  float*  x1_f = (float*) (ws + 70 * MB);   // 4MB
  bf16_t* m_b  = (bf16_t*)(ws + 74 * MB);   // 2MB
  bf16_t* h_b  = (bf16_t*)(ws + 76 * MB);   // 8MB
  bf16_t* wq_bf = (bf16_t*)(ws + 84 * MB);
  bf16_t* wk_bf = wq_bf + 524288;
  bf16_t* wv_bf = wk_bf + 524288;
  bf16_t* dw_bf = wv_bf + 524288;
  bf16_t* f1_bf = dw_bf + 524288;
  bf16_t* f2_bf = f1_bf + 262144;
  bf16_t* ctx_b = v_b;

  float* out0 = (float*)d_out;
  float* pout = out0 + 1048576;  // attn weights region

  cvt_w<<<128, 256, 0, stream>>>(wq_w, wq_bf, 131072);
  cvt_w<<<128, 256, 0, stream>>>(wk_w, wk_bf, 131072);
  cvt_w<<<128, 256, 0, stream>>>(wv_w, wv_bf, 131072);
  cvt_w<<<128, 256, 0, stream>>>(dw,   dw_bf, 131072);
  cvt_w<<<64, 256, 0, stream>>>(f1w, f1_bf, 65536);
  cvt_w<<<64, 256, 0, stream>>>(f2w, f2_bf, 65536);

  ln_k<<<1024, 256, 0, stream>>>(x, ln1g, ln1b, xn_f, xn_b);

  dim3 gq(16, 32);
  gemm_bt<M_QKV><<<gq, 256, 0, stream>>>(xn_b, wq_bf, wq_b, 256, 2048, q_b, nullptr);
  gemm_bt<M_QKV><<<gq, 256, 0, stream>>>(xn_b, wk_bf, wk_b, 256, 2048, k_b, nullptr);
  gemm_bt<M_QKV><<<gq, 256, 0, stream>>>(xn_b, wv_bf, wv_b, 256, 2048, v_b, nullptr);

  vtrans<<<dim3(32, 4, 16), 256, 0, stream>>>(v_b, vt_b);

  attn_k<<<512, 256, 0, stream>>>(q_b, k_b, vt_b, pout, ctx_b);

  gemm_bt<M_DENSE><<<dim3(2, 32), 256, 0, stream>>>(ctx_b, dw_bf, db, 2048, 256, x1_f, xn_f);

  ln_k<<<1024, 256, 0, stream>>>(x1_f, ln2g, ln2b, nullptr, m_b);

  gemm_bt<M_FC1><<<dim3(8, 32), 256, 0, stream>>>(m_b, f1_bf, f1b, 256, 1024, h_b, nullptr);
  gemm_bt<M_FC2><<<dim3(2, 32), 256, 0, stream>>>(h_b, f2_bf, f2b, 1024, 256, out0, x1_f);
}

// Round 2
// 233.262 us; speedup vs baseline: 1.2660x; 1.2660x over previous
//
#include <hip/hip_runtime.h>
#include <hip/hip_bf16.h>

// TransformerLayer on MI355X (gfx950). Round 1:
//  - 2-phase double-buffered GEMM core (counted vmcnt, raw s_barrier)
//  - fused QKV GEMM (one launch), fused weight-cvt (one launch)
//  - split-K x4 for dense and fc2 + reduce kernels
//  - attention kernel unchanged from round 0 (passed, isolate deltas)

typedef __bf16 bf16_t;
typedef __bf16 bf16x8 __attribute__((ext_vector_type(8)));
typedef __bf16 bf16x4 __attribute__((ext_vector_type(4)));
typedef float  f32x4  __attribute__((ext_vector_type(4)));

#define DEV __device__ __forceinline__

DEV f32x4 mfma16(bf16x8 a, bf16x8 b, f32x4 c) {
  return __builtin_amdgcn_mfma_f32_16x16x32_bf16(a, b, c, 0, 0, 0);
}

// async global->LDS, 16B per lane; lds base must be wave-uniform (HW adds lane*16)
DEV void gload16(const void* g, void* l) {
  __builtin_amdgcn_global_load_lds(
      (const __attribute__((address_space(1))) unsigned int*)g,
      (__attribute__((address_space(3))) unsigned int*)l, 16, 0, 0);
}

// ---------------- fused weight fp32 -> bf16 (all 6 weights, 1 launch) ----------------
__global__ __launch_bounds__(256) void cvt_all(
    const float* __restrict__ s0, const float* __restrict__ s1,
    const float* __restrict__ s2, const float* __restrict__ s3,
    const float* __restrict__ s4, const float* __restrict__ s5,
    bf16_t* __restrict__ d0, bf16_t* __restrict__ d1, bf16_t* __restrict__ d2,
    bf16_t* __restrict__ d3, bf16_t* __restrict__ d4, bf16_t* __restrict__ d5) {
  int i = blockIdx.x * 256 + threadIdx.x;   // float4 index, total 655360
  const float* s; bf16_t* d; int off;
  if      (i < 131072) { s = s0; d = d0; off = i; }
  else if (i < 262144) { s = s1; d = d1; off = i - 131072; }
  else if (i < 393216) { s = s2; d = d2; off = i - 262144; }
  else if (i < 524288) { s = s3; d = d3; off = i - 393216; }
  else if (i < 589824) { s = s4; d = d4; off = i - 524288; }
  else                 { s = s5; d = d5; off = i - 589824; }
  float4 v = ((const float4*)s)[off];
  bf16x4 o = { (bf16_t)v.x, (bf16_t)v.y, (bf16_t)v.z, (bf16_t)v.w };
  ((bf16x4*)d)[off] = o;
}

// ---------------- LayerNorm over 256, 1 wave per row ----------------
__global__ __launch_bounds__(256) void ln_k(const float* __restrict__ x,
    const float* __restrict__ g, const float* __restrict__ bta,
    float* __restrict__ of, bf16_t* __restrict__ ob) {
  int row = blockIdx.x * 4 + (threadIdx.x >> 6);
  int l = threadIdx.x & 63;
  const float4 v = *(const float4*)(x + (size_t)row * 256 + l * 4);
  float s  = v.x + v.y + v.z + v.w;
  float s2 = v.x*v.x + v.y*v.y + v.z*v.z + v.w*v.w;
#pragma unroll
  for (int o = 1; o < 64; o <<= 1) { s += __shfl_xor(s, o, 64); s2 += __shfl_xor(s2, o, 64); }
  float m   = s * (1.f/256.f);
  float var = s2 * (1.f/256.f) - m * m;
  float rs  = rsqrtf(var + 1e-9f);
  const float4 gv = *(const float4*)(g   + l * 4);
  const float4 bv = *(const float4*)(bta + l * 4);
  float4 y;
  y.x = (v.x - m) * rs * gv.x + bv.x;
  y.y = (v.y - m) * rs * gv.y + bv.y;
  y.z = (v.z - m) * rs * gv.z + bv.z;
  y.w = (v.w - m) * rs * gv.w + bv.w;
  if (of) *(float4*)(of + (size_t)row * 256 + l * 4) = y;
  bf16x4 yb = { (bf16_t)y.x, (bf16_t)y.y, (bf16_t)y.z, (bf16_t)y.w };
  *(bf16x4*)(ob + (size_t)row * 256 + l * 4) = yb;
}

// ---------------- 2-phase double-buffered 128x128 GEMM core ----------------
// C-tile = A(row0:+128, k0:k0+32*kiters) x W(col0:+128, same)^T, acc in regs.
// LDS: Asb/Bsb each 2 x 8192 bytes (128x32 bf16 per buffer).
DEV void gemm_core(const bf16_t* __restrict__ A, const bf16_t* __restrict__ W,
                   int lda, int row0, int col0, int k0, int kiters,
                   char* Asb, char* Bsb, f32x4 (&acc)[4][4]) {
  int tid = threadIdx.x, w = tid >> 6, l = tid & 63, l15 = l & 15, lhi = l >> 4;
  int wr = (w >> 1) * 64, wc = (w & 1) * 64;

#define STAGE(buf, kk) do {                                                   \
    char* Ad = Asb + (buf) * 8192 + w * 1024;                                 \
    char* Bd = Bsb + (buf) * 8192 + w * 1024;                                 \
    _Pragma("unroll")                                                         \
    for (int j = 0; j < 2; ++j) {                                             \
      int idx = (j * 256 + tid) * 8; int r = idx >> 5, c = idx & 31;          \
      gload16(A + (size_t)(row0 + r) * lda + (kk) + c, Ad + j * 4096);        \
      gload16(W + (size_t)(col0 + r) * lda + (kk) + c, Bd + j * 4096);        \
    } } while (0)

  STAGE(0, k0);
  for (int t = 0; t < kiters; ++t) {
    int cur = t & 1;
    if (t + 1 < kiters) {
      STAGE(cur ^ 1, k0 + (t + 1) * 32);
      asm volatile("s_waitcnt vmcnt(4)" ::: "memory");   // current tile landed
    } else {
      asm volatile("s_waitcnt vmcnt(0)" ::: "memory");
    }
    __builtin_amdgcn_s_barrier();
    asm volatile("" ::: "memory");
    const bf16_t* As = (const bf16_t*)(Asb + cur * 8192);
    const bf16_t* Bs = (const bf16_t*)(Bsb + cur * 8192);
    bf16x8 af[4], bfr[4];
#pragma unroll
    for (int m = 0; m < 4; ++m)
      af[m] = *(const bf16x8*)(As + (wr + 16 * m + l15) * 32 + lhi * 8);
#pragma unroll
    for (int n = 0; n < 4; ++n)
      bfr[n] = *(const bf16x8*)(Bs + (wc + 16 * n + l15) * 32 + lhi * 8);
#pragma unroll
    for (int m = 0; m < 4; ++m)
#pragma unroll
      for (int n = 0; n < 4; ++n)
        acc[m][n] = mfma16(af[m], bfr[n], acc[m][n]);
    asm volatile("" ::: "memory");
    __builtin_amdgcn_s_barrier();   // everyone done reading 'cur' before overwrite
  }
#undef STAGE
}

// ---------------- fused QKV: grid (48, 32) ----------------
__global__ __launch_bounds__(256, 2) void gemm_qkv(
    const bf16_t* __restrict__ A,
    const bf16_t* __restrict__ W0, const bf16_t* __restrict__ W1, const bf16_t* __restrict__ W2,
    const float* __restrict__ b0, const float* __restrict__ b1, const float* __restrict__ b2,
    bf16_t* __restrict__ qo, bf16_t* __restrict__ ko, bf16_t* __restrict__ vo) {
  __shared__ char Asb[2 * 8192];
  __shared__ char Bsb[2 * 8192];
  int bx = blockIdx.x;
  int wsel = bx >> 4, cb = bx & 15;
  const bf16_t* W    = wsel == 0 ? W0 : (wsel == 1 ? W1 : W2);
  const float*  bias = wsel == 0 ? b0 : (wsel == 1 ? b1 : b2);
  bf16_t*       out  = wsel == 0 ? qo : (wsel == 1 ? ko : vo);
  int row0 = blockIdx.y * 128, col0 = cb * 128;
  f32x4 acc[4][4] = {};
  gemm_core(A, W, 256, row0, col0, 0, 8, Asb, Bsb, acc);

  int tid = threadIdx.x, w = tid >> 6, l = tid & 63, l15 = l & 15, lhi = l >> 4;
  int wr = (w >> 1) * 64, wc = (w & 1) * 64;
#pragma unroll
  for (int m = 0; m < 4; ++m)
#pragma unroll
    for (int n = 0; n < 4; ++n)
#pragma unroll
      for (int j = 0; j < 4; ++j) {
        int row = row0 + wr + 16 * m + lhi * 4 + j;
        int col = col0 + wc + 16 * n + l15;
        float v = acc[m][n][j] + bias[col];
        // (B,H,S,Dh): b=row>>11, s=row&2047, h=col>>8, d=col&255
        out[((size_t)((row >> 11) * 8 + (col >> 8)) * 2048 + (row & 2047)) * 256 + (col & 255)] = (bf16_t)v;
      }
}

// ---------------- split-K partial GEMM: N=256, grid (2, 32, SPLIT) ----------------
__global__ __launch_bounds__(256, 2) void gemm_part(
    const bf16_t* __restrict__ A, const bf16_t* __restrict__ W,
    int lda, int ksub, float* __restrict__ parts) {
  __shared__ char Asb[2 * 8192];
  __shared__ char Bsb[2 * 8192];
  int z = blockIdx.z;
  int row0 = blockIdx.y * 128, col0 = blockIdx.x * 128;
  f32x4 acc[4][4] = {};
  gemm_core(A, W, lda, row0, col0, z * ksub, ksub >> 5, Asb, Bsb, acc);

  int tid = threadIdx.x, w = tid >> 6, l = tid & 63, l15 = l & 15, lhi = l >> 4;
  int wr = (w >> 1) * 64, wc = (w & 1) * 64;
  float* p = parts + (size_t)z * 1048576;
#pragma unroll
  for (int m = 0; m < 4; ++m)
#pragma unroll
    for (int n = 0; n < 4; ++n)
#pragma unroll
      for (int j = 0; j < 4; ++j) {
        int row = row0 + wr + 16 * m + lhi * 4 + j;
        int col = col0 + wc + 16 * n + l15;
        p[(size_t)row * 256 + col] = acc[m][n][j];
      }
}

// ---------------- reduce 4 partials + bias + residual ----------------
__global__ __launch_bounds__(256) void reduce4(
    const float* __restrict__ parts, const float* __restrict__ bias,
    const float* __restrict__ res, float* __restrict__ out) {
  int i = blockIdx.x * 256 + threadIdx.x;   // float4 index, 262144 total
  f32x4 s = *(const f32x4*)(parts + (size_t)i * 4);
  s += *(const f32x4*)(parts + 1048576 + (size_t)i * 4);
  s += *(const f32x4*)(parts + 2097152 + (size_t)i * 4);
  s += *(const f32x4*)(parts + 3145728 + (size_t)i * 4);
  s += *(const f32x4*)(res + (size_t)i * 4);
  s += *(const f32x4*)(bias + (i & 63) * 4);
  *(f32x4*)(out + (size_t)i * 4) = s;
}

// ---------------- FC1 with gelu epilogue: grid (8, 32) ----------------
__global__ __launch_bounds__(256, 2) void gemm_fc1(
    const bf16_t* __restrict__ A, const bf16_t* __restrict__ W,
    const float* __restrict__ bias, bf16_t* __restrict__ out) {
  __shared__ char Asb[2 * 8192];
  __shared__ char Bsb[2 * 8192];
  int row0 = blockIdx.y * 128, col0 = blockIdx.x * 128;
  f32x4 acc[4][4] = {};
  gemm_core(A, W, 256, row0, col0, 0, 8, Asb, Bsb, acc);

  int tid = threadIdx.x, w = tid >> 6, l = tid & 63, l15 = l & 15, lhi = l >> 4;
  int wr = (w >> 1) * 64, wc = (w & 1) * 64;
#pragma unroll
  for (int m = 0; m < 4; ++m)
#pragma unroll
    for (int n = 0; n < 4; ++n)
#pragma unroll
      for (int j = 0; j < 4; ++j) {
        int row = row0 + wr + 16 * m + lhi * 4 + j;
        int col = col0 + wc + 16 * n + l15;
        float t = acc[m][n][j] + bias[col];
        float ge = 0.5f * t * (1.f + tanhf(0.7978845608f * t * (1.f + 0.044715f * t * t)));
        out[(size_t)row * 1024 + col] = (bf16_t)ge;
      }
}

// ---------------- V (B,H,S,Dh) -> V^T (B,H,Dh,S) ----------------
__global__ __launch_bounds__(256) void vtrans(const bf16_t* __restrict__ v, bf16_t* __restrict__ vt) {
  __shared__ bf16_t t[64 * 72];
  int bh = blockIdx.z;
  int s0 = blockIdx.x * 64, d0 = blockIdx.y * 64;
  int tid = threadIdx.x;
#pragma unroll
  for (int j = 0; j < 2; ++j) {
    int cj = j * 256 + tid;
    int r = cj >> 3, c = (cj & 7) * 8;
    *(bf16x8*)(t + r * 72 + c) = *(const bf16x8*)(v + ((size_t)bh * 2048 + s0 + r) * 256 + d0 + c);
  }
  __syncthreads();
#pragma unroll
  for (int j = 0; j < 2; ++j) {
    int cj = j * 256 + tid;
    int rd = cj >> 3, cs = (cj & 7) * 8;
    bf16x8 o;
#pragma unroll
    for (int i = 0; i < 8; ++i) o[i] = t[(cs + i) * 72 + rd];
    *(bf16x8*)(vt + ((size_t)bh * 256 + d0 + rd) * 2048 + s0 + cs) = o;
  }
}

// ---------------- fused causal attention, Q-tile=64, K-tile=64 ----------------
__global__ __launch_bounds__(256, 2) void attn_k(
    const bf16_t* __restrict__ qg, const bf16_t* __restrict__ kg,
    const bf16_t* __restrict__ vt, float* __restrict__ pout,
    bf16_t* __restrict__ ctxo) {
  __shared__ bf16_t Ksh[64 * 256];   // 32KB, XOR-swizzled rows (512B)
  __shared__ bf16_t Vsh[256 * 64];   // 32KB, V^T tile, XOR-swizzled rows (128B)
  __shared__ bf16_t Psh[64 * 64];    // 8KB,  XOR-swizzled rows (128B)
  int bx = blockIdx.x;
  int bh = bx & 15, qt = 31 - (bx >> 4);
  int tid = threadIdx.x, w = tid >> 6, l = tid & 63;
  int l15 = l & 15, lhi = l >> 4, l7 = l & 7;
  const bf16_t* Q   = qg + (size_t)bh * 2048 * 256;
  const bf16_t* Kg2 = kg + (size_t)bh * 2048 * 256;
  const bf16_t* Vt  = vt + (size_t)bh * 256 * 2048;
  int qbase = qt * 64;

  bf16x8 qf[8];
#pragma unroll
  for (int ks = 0; ks < 8; ++ks)
    qf[ks] = *(const bf16x8*)(Q + (size_t)(qbase + w * 16 + l15) * 256 + ks * 32 + lhi * 8);

  // ---- pass A: rowsum of exp ----
  float sums[4] = {0.f, 0.f, 0.f, 0.f};
  for (int kt = 0; kt <= qt; ++kt) {
    __syncthreads();
#pragma unroll
    for (int j = 0; j < 8; ++j) {
      int p = (j * 256 + tid) * 16;
      int r = p >> 9;
      int co = (p & 511) ^ ((r & 7) << 4);
      gload16(Kg2 + (size_t)(kt * 64 + r) * 256 + (co >> 1), (char*)Ksh + j * 4096 + w * 1024);
    }
    __syncthreads();
    f32x4 acc[4] = {};
#pragma unroll
    for (int ks = 0; ks < 8; ++ks) {
#pragma unroll
      for (int n = 0; n < 4; ++n) {
        bf16x8 kb = *(const bf16x8*)((const char*)Ksh + (16 * n + l15) * 512 + ((ks * 64 + lhi * 16) ^ (l7 << 4)));
        acc[n] = mfma16(qf[ks], kb, acc[n]);
      }
    }
#pragma unroll
    for (int n = 0; n < 4; ++n)
#pragma unroll
      for (int j = 0; j < 4; ++j) {
        int kc = kt * 64 + 16 * n + l15;
        int qr = qbase + w * 16 + lhi * 4 + j;
        sums[j] += (kc <= qr) ? __expf(acc[n][j] * 0.0625f) : 0.f;
      }
  }
#pragma unroll
  for (int j = 0; j < 4; ++j) {
#pragma unroll
    for (int o = 1; o < 16; o <<= 1) sums[j] += __shfl_xor(sums[j], o, 64);
    sums[j] = 1.f / sums[j];
  }

  // ---- pass B: P writes + PV ----
  f32x4 ctx[16] = {};
  for (int kt = 0; kt <= qt; ++kt) {
    __syncthreads();
#pragma unroll
    for (int j = 0; j < 8; ++j) {
      int p = (j * 256 + tid) * 16;
      { int r = p >> 9; int co = (p & 511) ^ ((r & 7) << 4);
        gload16(Kg2 + (size_t)(kt * 64 + r) * 256 + (co >> 1), (char*)Ksh + j * 4096 + w * 1024); }
      { int r = p >> 7; int co = (p & 127) ^ ((r & 7) << 4);
        gload16(Vt + (size_t)r * 2048 + kt * 64 + (co >> 1), (char*)Vsh + j * 4096 + w * 1024); }
    }
    __syncthreads();
    f32x4 acc[4] = {};
#pragma unroll
    for (int ks = 0; ks < 8; ++ks) {
#pragma unroll
      for (int n = 0; n < 4; ++n) {
        bf16x8 kb = *(const bf16x8*)((const char*)Ksh + (16 * n + l15) * 512 + ((ks * 64 + lhi * 16) ^ (l7 << 4)));
        acc[n] = mfma16(qf[ks], kb, acc[n]);
      }
    }
#pragma unroll
    for (int n = 0; n < 4; ++n) {
#pragma unroll
      for (int j = 0; j < 4; ++j) {
        int kc = kt * 64 + 16 * n + l15;
        int qr = qbase + w * 16 + lhi * 4 + j;
        float e = (kc <= qr) ? __expf(acc[n][j] * 0.0625f) * sums[j] : 0.f;
        pout[((size_t)bh * 2048 + qr) * 2048 + kc] = e;
        int prow = w * 16 + lhi * 4 + j;
        int pcb = (16 * n + l15) * 2;
        *(bf16_t*)((char*)Psh + prow * 128 + (pcb ^ ((prow & 7) << 4))) = (bf16_t)e;
      }
    }
    __syncthreads();
#pragma unroll
    for (int k2 = 0; k2 < 2; ++k2) {
      bf16x8 pa = *(const bf16x8*)((const char*)Psh + (w * 16 + l15) * 128 + ((k2 * 64 + lhi * 16) ^ (l7 << 4)));
#pragma unroll
      for (int n = 0; n < 16; ++n) {
        bf16x8 vb = *(const bf16x8*)((const char*)Vsh + (16 * n + l15) * 128 + ((k2 * 64 + lhi * 16) ^ (l7 << 4)));
        ctx[n] = mfma16(pa, vb, ctx[n]);
      }
    }
  }

  int b = bh >> 3, h = bh & 7;
#pragma unroll
  for (int n = 0; n < 16; ++n)
#pragma unroll
    for (int j = 0; j < 4; ++j) {
      int qr = qbase + w * 16 + lhi * 4 + j;
      ctxo[((size_t)b * 2048 + qr) * 2048 + h * 256 + 16 * n + l15] = (bf16_t)ctx[n][j];
    }

  int zs = qbase + 64;
  for (int r = 0; r < 64; ++r) {
    size_t base = ((size_t)bh * 2048 + qbase + r) * 2048;
    for (int c = zs + tid * 4; c < 2048; c += 1024) {
      *(float4*)(pout + base + c) = make_float4(0.f, 0.f, 0.f, 0.f);
    }
  }
}

// ---------------- host launch ----------------
extern "C" void kernel_launch(void* const* d_in, const int* in_sizes, int n_in,
                              void* d_out, int out_size, void* d_ws, size_t ws_size,
                              hipStream_t stream) {
  const float* x     = (const float*)d_in[0];
  const float* ln1g  = (const float*)d_in[2];
  const float* ln1b  = (const float*)d_in[3];
  const float* wq_w  = (const float*)d_in[4];
  const float* wq_b  = (const float*)d_in[5];
  const float* wk_w  = (const float*)d_in[6];
  const float* wk_b  = (const float*)d_in[7];
  const float* wv_w  = (const float*)d_in[8];
  const float* wv_b  = (const float*)d_in[9];
  const float* dw    = (const float*)d_in[10];
  const float* db    = (const float*)d_in[11];
  const float* ln2g  = (const float*)d_in[12];
  const float* ln2b  = (const float*)d_in[13];
  const float* f1w   = (const float*)d_in[14];
  const float* f1b   = (const float*)d_in[15];
  const float* f2w   = (const float*)d_in[16];
  const float* f2b   = (const float*)d_in[17];

  char* ws = (char*)d_ws;
  const size_t MB = 1u << 20;
  float*  xn_f = (float*) (ws + 0 * MB);    // 4MB
  bf16_t* xn_b = (bf16_t*)(ws + 4 * MB);    // 2MB
  bf16_t* q_b  = (bf16_t*)(ws + 6 * MB);    // 16MB (dead after attn -> dense parts)
  bf16_t* k_b  = (bf16_t*)(ws + 22 * MB);   // 16MB (dead after attn -> fc2 parts)
  bf16_t* v_b  = (bf16_t*)(ws + 38 * MB);   // 16MB (reused as ctx)
  bf16_t* vt_b = (bf16_t*)(ws + 54 * MB);   // 16MB
  float*  x1_f = (float*) (ws + 70 * MB);   // 4MB
  bf16_t* m_b  = (bf16_t*)(ws + 74 * MB);   // 2MB
  bf16_t* h_b  = (bf16_t*)(ws + 76 * MB);   // 8MB
  bf16_t* wq_bf = (bf16_t*)(ws + 84 * MB);
  bf16_t* wk_bf = wq_bf + 524288;
  bf16_t* wv_bf = wk_bf + 524288;
  bf16_t* dw_bf = wv_bf + 524288;
  bf16_t* f1_bf = dw_bf + 524288;
  bf16_t* f2_bf = f1_bf + 262144;
  bf16_t* ctx_b = v_b;
  float* parts_d = (float*)q_b;   // 16MB, used after attn
  float* parts_f = (float*)k_b;   // 16MB, used after attn

  float* out0 = (float*)d_out;
  float* pout = out0 + 1048576;   // attn weights region

  cvt_all<<<2560, 256, 0, stream>>>(wq_w, wk_w, wv_w, dw, f1w, f2w,
                                    wq_bf, wk_bf, wv_bf, dw_bf, f1_bf, f2_bf);

  ln_k<<<1024, 256, 0, stream>>>(x, ln1g, ln1b, xn_f, xn_b);

  gemm_qkv<<<dim3(48, 32), 256, 0, stream>>>(xn_b, wq_bf, wk_bf, wv_bf,
                                             wq_b, wk_b, wv_b, q_b, k_b, v_b);

  vtrans<<<dim3(32, 4, 16), 256, 0, stream>>>(v_b, vt_b);

  attn_k<<<512, 256, 0, stream>>>(q_b, k_b, vt_b, pout, ctx_b);

  gemm_part<<<dim3(2, 32, 4), 256, 0, stream>>>(ctx_b, dw_bf, 2048, 512, parts_d);
  reduce4<<<1024, 256, 0, stream>>>(parts_d, db, xn_f, x1_f);

  ln_k<<<1024, 256, 0, stream>>>(x1_f, ln2g, ln2b, nullptr, m_b);

  gemm_fc1<<<dim3(8, 32), 256, 0, stream>>>(m_b, f1_bf, f1b, h_b);

  gemm_part<<<dim3(2, 32, 4), 256, 0, stream>>>(h_b, f2_bf, 1024, 256, parts_f);
  reduce4<<<1024, 256, 0, stream>>>(parts_f, f2b, x1_f, out0);
}

// Round 3
// 229.500 us; speedup vs baseline: 1.2868x; 1.0164x over previous
//
#include <hip/hip_runtime.h>
#include <hip/hip_bf16.h>

// TransformerLayer on MI355X (gfx950). Round 2:
//  - attention split: rowsum kernel (QK^T+exp+masked sum, K-dbuf, counted vmcnt)
//    + pass-B kernel (TK=32, K/V double-buffered, no vmcnt(0) in loop,
//    P written normalized via LDS->float4, d-split PV)
//  - GEMM stack unchanged from round 1 (233us baseline)

typedef __bf16 bf16_t;
typedef __bf16 bf16x8 __attribute__((ext_vector_type(8)));
typedef __bf16 bf16x4 __attribute__((ext_vector_type(4)));
typedef float  f32x4  __attribute__((ext_vector_type(4)));

#define DEV __device__ __forceinline__

DEV f32x4 mfma16(bf16x8 a, bf16x8 b, f32x4 c) {
  return __builtin_amdgcn_mfma_f32_16x16x32_bf16(a, b, c, 0, 0, 0);
}

DEV void gload16(const void* g, void* l) {
  __builtin_amdgcn_global_load_lds(
      (const __attribute__((address_space(1))) unsigned int*)g,
      (__attribute__((address_space(3))) unsigned int*)l, 16, 0, 0);
}

// ---------------- fused weight fp32 -> bf16 ----------------
__global__ __launch_bounds__(256) void cvt_all(
    const float* __restrict__ s0, const float* __restrict__ s1,
    const float* __restrict__ s2, const float* __restrict__ s3,
    const float* __restrict__ s4, const float* __restrict__ s5,
    bf16_t* __restrict__ d0, bf16_t* __restrict__ d1, bf16_t* __restrict__ d2,
    bf16_t* __restrict__ d3, bf16_t* __restrict__ d4, bf16_t* __restrict__ d5) {
  int i = blockIdx.x * 256 + threadIdx.x;
  const float* s; bf16_t* d; int off;
  if      (i < 131072) { s = s0; d = d0; off = i; }
  else if (i < 262144) { s = s1; d = d1; off = i - 131072; }
  else if (i < 393216) { s = s2; d = d2; off = i - 262144; }
  else if (i < 524288) { s = s3; d = d3; off = i - 393216; }
  else if (i < 589824) { s = s4; d = d4; off = i - 524288; }
  else                 { s = s5; d = d5; off = i - 589824; }
  float4 v = ((const float4*)s)[off];
  bf16x4 o = { (bf16_t)v.x, (bf16_t)v.y, (bf16_t)v.z, (bf16_t)v.w };
  ((bf16x4*)d)[off] = o;
}

// ---------------- LayerNorm over 256, 1 wave per row ----------------
__global__ __launch_bounds__(256) void ln_k(const float* __restrict__ x,
    const float* __restrict__ g, const float* __restrict__ bta,
    float* __restrict__ of, bf16_t* __restrict__ ob) {
  int row = blockIdx.x * 4 + (threadIdx.x >> 6);
  int l = threadIdx.x & 63;
  const float4 v = *(const float4*)(x + (size_t)row * 256 + l * 4);
  float s  = v.x + v.y + v.z + v.w;
  float s2 = v.x*v.x + v.y*v.y + v.z*v.z + v.w*v.w;
#pragma unroll
  for (int o = 1; o < 64; o <<= 1) { s += __shfl_xor(s, o, 64); s2 += __shfl_xor(s2, o, 64); }
  float m   = s * (1.f/256.f);
  float var = s2 * (1.f/256.f) - m * m;
  float rs  = rsqrtf(var + 1e-9f);
  const float4 gv = *(const float4*)(g   + l * 4);
  const float4 bv = *(const float4*)(bta + l * 4);
  float4 y;
  y.x = (v.x - m) * rs * gv.x + bv.x;
  y.y = (v.y - m) * rs * gv.y + bv.y;
  y.z = (v.z - m) * rs * gv.z + bv.z;
  y.w = (v.w - m) * rs * gv.w + bv.w;
  if (of) *(float4*)(of + (size_t)row * 256 + l * 4) = y;
  bf16x4 yb = { (bf16_t)y.x, (bf16_t)y.y, (bf16_t)y.z, (bf16_t)y.w };
  *(bf16x4*)(ob + (size_t)row * 256 + l * 4) = yb;
}

// ---------------- 2-phase double-buffered 128x128 GEMM core ----------------
DEV void gemm_core(const bf16_t* __restrict__ A, const bf16_t* __restrict__ W,
                   int lda, int row0, int col0, int k0, int kiters,
                   char* Asb, char* Bsb, f32x4 (&acc)[4][4]) {
  int tid = threadIdx.x, w = tid >> 6, l = tid & 63, l15 = l & 15, lhi = l >> 4;
  int wr = (w >> 1) * 64, wc = (w & 1) * 64;

#define STAGE(buf, kk) do {                                                   \
    char* Ad = Asb + (buf) * 8192 + w * 1024;                                 \
    char* Bd = Bsb + (buf) * 8192 + w * 1024;                                 \
    _Pragma("unroll")                                                         \
    for (int j = 0; j < 2; ++j) {                                             \
      int idx = (j * 256 + tid) * 8; int r = idx >> 5, c = idx & 31;          \
      gload16(A + (size_t)(row0 + r) * lda + (kk) + c, Ad + j * 4096);        \
      gload16(W + (size_t)(col0 + r) * lda + (kk) + c, Bd + j * 4096);        \
    } } while (0)

  STAGE(0, k0);
  for (int t = 0; t < kiters; ++t) {
    int cur = t & 1;
    if (t + 1 < kiters) {
      STAGE(cur ^ 1, k0 + (t + 1) * 32);
      asm volatile("s_waitcnt vmcnt(4)" ::: "memory");
    } else {
      asm volatile("s_waitcnt vmcnt(0)" ::: "memory");
    }
    __builtin_amdgcn_s_barrier();
    asm volatile("" ::: "memory");
    const bf16_t* As = (const bf16_t*)(Asb + cur * 8192);
    const bf16_t* Bs = (const bf16_t*)(Bsb + cur * 8192);
    bf16x8 af[4], bfr[4];
#pragma unroll
    for (int m = 0; m < 4; ++m)
      af[m] = *(const bf16x8*)(As + (wr + 16 * m + l15) * 32 + lhi * 8);
#pragma unroll
    for (int n = 0; n < 4; ++n)
      bfr[n] = *(const bf16x8*)(Bs + (wc + 16 * n + l15) * 32 + lhi * 8);
#pragma unroll
    for (int m = 0; m < 4; ++m)
#pragma unroll
      for (int n = 0; n < 4; ++n)
        acc[m][n] = mfma16(af[m], bfr[n], acc[m][n]);
    asm volatile("" ::: "memory");
    __builtin_amdgcn_s_barrier();
  }
#undef STAGE
}

// ---------------- fused QKV ----------------
__global__ __launch_bounds__(256, 2) void gemm_qkv(
    const bf16_t* __restrict__ A,
    const bf16_t* __restrict__ W0, const bf16_t* __restrict__ W1, const bf16_t* __restrict__ W2,
    const float* __restrict__ b0, const float* __restrict__ b1, const float* __restrict__ b2,
    bf16_t* __restrict__ qo, bf16_t* __restrict__ ko, bf16_t* __restrict__ vo) {
  __shared__ char Asb[2 * 8192];
  __shared__ char Bsb[2 * 8192];
  int bx = blockIdx.x;
  int wsel = bx >> 4, cb = bx & 15;
  const bf16_t* W    = wsel == 0 ? W0 : (wsel == 1 ? W1 : W2);
  const float*  bias = wsel == 0 ? b0 : (wsel == 1 ? b1 : b2);
  bf16_t*       out  = wsel == 0 ? qo : (wsel == 1 ? ko : vo);
  int row0 = blockIdx.y * 128, col0 = cb * 128;
  f32x4 acc[4][4] = {};
  gemm_core(A, W, 256, row0, col0, 0, 8, Asb, Bsb, acc);

  int tid = threadIdx.x, w = tid >> 6, l = tid & 63, l15 = l & 15, lhi = l >> 4;
  int wr = (w >> 1) * 64, wc = (w & 1) * 64;
#pragma unroll
  for (int m = 0; m < 4; ++m)
#pragma unroll
    for (int n = 0; n < 4; ++n)
#pragma unroll
      for (int j = 0; j < 4; ++j) {
        int row = row0 + wr + 16 * m + lhi * 4 + j;
        int col = col0 + wc + 16 * n + l15;
        float v = acc[m][n][j] + bias[col];
        out[((size_t)((row >> 11) * 8 + (col >> 8)) * 2048 + (row & 2047)) * 256 + (col & 255)] = (bf16_t)v;
      }
}

// ---------------- split-K partial GEMM ----------------
__global__ __launch_bounds__(256, 2) void gemm_part(
    const bf16_t* __restrict__ A, const bf16_t* __restrict__ W,
    int lda, int ksub, float* __restrict__ parts) {
  __shared__ char Asb[2 * 8192];
  __shared__ char Bsb[2 * 8192];
  int z = blockIdx.z;
  int row0 = blockIdx.y * 128, col0 = blockIdx.x * 128;
  f32x4 acc[4][4] = {};
  gemm_core(A, W, lda, row0, col0, z * ksub, ksub >> 5, Asb, Bsb, acc);

  int tid = threadIdx.x, w = tid >> 6, l = tid & 63, l15 = l & 15, lhi = l >> 4;
  int wr = (w >> 1) * 64, wc = (w & 1) * 64;
  float* p = parts + (size_t)z * 1048576;
#pragma unroll
  for (int m = 0; m < 4; ++m)
#pragma unroll
    for (int n = 0; n < 4; ++n)
#pragma unroll
      for (int j = 0; j < 4; ++j) {
        int row = row0 + wr + 16 * m + lhi * 4 + j;
        int col = col0 + wc + 16 * n + l15;
        p[(size_t)row * 256 + col] = acc[m][n][j];
      }
}

// ---------------- reduce 4 partials + bias + residual ----------------
__global__ __launch_bounds__(256) void reduce4(
    const float* __restrict__ parts, const float* __restrict__ bias,
    const float* __restrict__ res, float* __restrict__ out) {
  int i = blockIdx.x * 256 + threadIdx.x;
  f32x4 s = *(const f32x4*)(parts + (size_t)i * 4);
  s += *(const f32x4*)(parts + 1048576 + (size_t)i * 4);
  s += *(const f32x4*)(parts + 2097152 + (size_t)i * 4);
  s += *(const f32x4*)(parts + 3145728 + (size_t)i * 4);
  s += *(const f32x4*)(res + (size_t)i * 4);
  s += *(const f32x4*)(bias + (i & 63) * 4);
  *(f32x4*)(out + (size_t)i * 4) = s;
}

// ---------------- FC1 with gelu ----------------
__global__ __launch_bounds__(256, 2) void gemm_fc1(
    const bf16_t* __restrict__ A, const bf16_t* __restrict__ W,
    const float* __restrict__ bias, bf16_t* __restrict__ out) {
  __shared__ char Asb[2 * 8192];
  __shared__ char Bsb[2 * 8192];
  int row0 = blockIdx.y * 128, col0 = blockIdx.x * 128;
  f32x4 acc[4][4] = {};
  gemm_core(A, W, 256, row0, col0, 0, 8, Asb, Bsb, acc);

  int tid = threadIdx.x, w = tid >> 6, l = tid & 63, l15 = l & 15, lhi = l >> 4;
  int wr = (w >> 1) * 64, wc = (w & 1) * 64;
#pragma unroll
  for (int m = 0; m < 4; ++m)
#pragma unroll
    for (int n = 0; n < 4; ++n)
#pragma unroll
      for (int j = 0; j < 4; ++j) {
        int row = row0 + wr + 16 * m + lhi * 4 + j;
        int col = col0 + wc + 16 * n + l15;
        float t = acc[m][n][j] + bias[col];
        float ge = 0.5f * t * (1.f + tanhf(0.7978845608f * t * (1.f + 0.044715f * t * t)));
        out[(size_t)row * 1024 + col] = (bf16_t)ge;
      }
}

// ---------------- V (B,H,S,Dh) -> V^T (B,H,Dh,S) ----------------
__global__ __launch_bounds__(256) void vtrans(const bf16_t* __restrict__ v, bf16_t* __restrict__ vt) {
  __shared__ bf16_t t[64 * 72];
  int bh = blockIdx.z;
  int s0 = blockIdx.x * 64, d0 = blockIdx.y * 64;
  int tid = threadIdx.x;
#pragma unroll
  for (int j = 0; j < 2; ++j) {
    int cj = j * 256 + tid;
    int r = cj >> 3, c = (cj & 7) * 8;
    *(bf16x8*)(t + r * 72 + c) = *(const bf16x8*)(v + ((size_t)bh * 2048 + s0 + r) * 256 + d0 + c);
  }
  __syncthreads();
#pragma unroll
  for (int j = 0; j < 2; ++j) {
    int cj = j * 256 + tid;
    int rd = cj >> 3, cs = (cj & 7) * 8;
    bf16x8 o;
#pragma unroll
    for (int i = 0; i < 8; ++i) o[i] = t[(cs + i) * 72 + rd];
    *(bf16x8*)(vt + ((size_t)bh * 256 + d0 + rd) * 2048 + s0 + cs) = o;
  }
}

// ---------------- rowsum kernel: sums[bh][qr] = 1/sum_k exp(S) ----------------
// QBLK=64, TK=64, K double-buffered, counted vmcnt, 2 barriers/tile.
// Waves 2x2: (wm,wn); wave computes rows [wm*32,+32) x cols [wn*32,+32).
__global__ __launch_bounds__(256, 2) void rowsum_k(
    const bf16_t* __restrict__ qg, const bf16_t* __restrict__ kg,
    float* __restrict__ rsg) {
  __shared__ bf16_t Ksh[2][64 * 256];   // 2 x 32KB
  __shared__ float  sl[2][64];
  int bx = blockIdx.x;
  int bh = bx & 15, qt = 31 - (bx >> 4);
  int tid = threadIdx.x, w = tid >> 6, l = tid & 63;
  int l15 = l & 15, lhi = l >> 4;
  int wm = w >> 1, wn = w & 1;
  const bf16_t* Q   = qg + (size_t)bh * 2048 * 256;
  const bf16_t* Kg2 = kg + (size_t)bh * 2048 * 256;
  int qbase = qt * 64;
  int nkt = qt + 1;   // TK=64 tiles

  // Q fragments: rows qbase + wm*32 + m*16 + l15
  bf16x8 qf[2][8];
#pragma unroll
  for (int m = 0; m < 2; ++m)
#pragma unroll
    for (int ks = 0; ks < 8; ++ks)
      qf[m][ks] = *(const bf16x8*)(Q + (size_t)(qbase + wm * 32 + m * 16 + l15) * 256 + ks * 32 + lhi * 8);

#define RSTAGE(t_) do {                                                        \
    char* dst = (char*)Ksh[(t_) & 1] + w * 1024;                               \
    _Pragma("unroll")                                                          \
    for (int j = 0; j < 8; ++j) {                                              \
      int idx = (j * 256 + tid) * 16; int r = idx >> 9;                        \
      int co = (idx & 511) ^ ((r & 7) << 4);                                   \
      gload16(Kg2 + (size_t)((t_) * 64 + r) * 256 + (co >> 1), dst + j * 4096);\
    } } while (0)

  RSTAGE(0);
  if (nkt > 1) RSTAGE(1);

  float sums[2][4] = {};
  for (int t = 0; t < nkt; ++t) {
    if (t + 1 < nkt) asm volatile("s_waitcnt vmcnt(8)" ::: "memory");
    else             asm volatile("s_waitcnt vmcnt(0)" ::: "memory");
    __builtin_amdgcn_s_barrier();
    const char* Kb = (const char*)Ksh[t & 1];
    f32x4 acc[2][2] = {};
#pragma unroll
    for (int ks = 0; ks < 8; ++ks) {
#pragma unroll
      for (int n2 = 0; n2 < 2; ++n2) {
        int row = wn * 32 + n2 * 16 + l15;
        bf16x8 kb = *(const bf16x8*)(Kb + row * 512 + ((ks * 64 + lhi * 16) ^ ((row & 7) << 4)));
#pragma unroll
        for (int m = 0; m < 2; ++m)
          acc[m][n2] = mfma16(qf[m][ks], kb, acc[m][n2]);
      }
    }
#pragma unroll
    for (int m = 0; m < 2; ++m)
#pragma unroll
      for (int n2 = 0; n2 < 2; ++n2)
#pragma unroll
        for (int j = 0; j < 4; ++j) {
          int qr = qbase + wm * 32 + m * 16 + lhi * 4 + j;
          int kc = t * 64 + wn * 32 + n2 * 16 + l15;
          sums[m][j] += (kc <= qr) ? __expf(acc[m][n2][j] * 0.0625f) : 0.f;
        }
    asm volatile("" ::: "memory");
    __builtin_amdgcn_s_barrier();   // all K reads done before overwrite
    if (t + 2 < nkt) RSTAGE(t + 2);
  }
#undef RSTAGE

  // reduce over l15 (16 lanes) within same lhi
#pragma unroll
  for (int m = 0; m < 2; ++m)
#pragma unroll
    for (int j = 0; j < 4; ++j) {
#pragma unroll
      for (int o = 1; o < 16; o <<= 1) sums[m][j] += __shfl_xor(sums[m][j], o, 64);
    }
  if (l15 == 0) {
#pragma unroll
    for (int m = 0; m < 2; ++m)
#pragma unroll
      for (int j = 0; j < 4; ++j)
        sl[wn][wm * 32 + m * 16 + lhi * 4 + j] = sums[m][j];
  }
  __syncthreads();
  if (tid < 64)
    rsg[(size_t)bh * 2048 + qbase + tid] = 1.f / (sl[0][tid] + sl[1][tid]);
}

// ---------------- attention pass B: P-write + PV, TK=32, full dbuf ----------------
__global__ __launch_bounds__(256, 2) void attn_pv(
    const bf16_t* __restrict__ qg, const bf16_t* __restrict__ kg,
    const bf16_t* __restrict__ vt, const float* __restrict__ rsg,
    float* __restrict__ pout, bf16_t* __restrict__ ctxo) {
  __shared__ bf16_t Ksh[2][32 * 256];   // 2 x 16KB
  __shared__ bf16_t Vsh[2][256 * 32];   // 2 x 16KB  (V^T rows d, 64B rows)
  __shared__ bf16_t Psh[64 * 32];       // 4KB
  int bx = blockIdx.x;
  int bh = bx & 15, qt = 31 - (bx >> 4);
  int tid = threadIdx.x, w = tid >> 6, l = tid & 63;
  int l15 = l & 15, lhi = l >> 4;
  int wm = w >> 1, wn = w & 1;
  const bf16_t* Q   = qg + (size_t)bh * 2048 * 256;
  const bf16_t* Kg2 = kg + (size_t)bh * 2048 * 256;
  const bf16_t* Vt  = vt + (size_t)bh * 256 * 2048;
  int qbase = qt * 64;
  int nkt = 2 * (qt + 1);   // TK=32 tiles

  // Q fragments: rows qbase + wm*32 + m*16 + l15
  bf16x8 qf[2][8];
#pragma unroll
  for (int m = 0; m < 2; ++m)
#pragma unroll
    for (int ks = 0; ks < 8; ++ks)
      qf[m][ks] = *(const bf16x8*)(Q + (size_t)(qbase + wm * 32 + m * 16 + l15) * 256 + ks * 32 + lhi * 8);

  // inverse rowsums for this lane's 8 rows
  float inv[8];
#pragma unroll
  for (int m = 0; m < 2; ++m)
#pragma unroll
    for (int j = 0; j < 4; ++j)
      inv[m * 4 + j] = rsg[(size_t)bh * 2048 + qbase + wm * 32 + m * 16 + lhi * 4 + j];

#define PSTAGE(t_) do {                                                         \
    char* kd = (char*)Ksh[(t_) & 1] + w * 1024;                                 \
    char* vd = (char*)Vsh[(t_) & 1] + w * 1024;                                 \
    _Pragma("unroll")                                                           \
    for (int j = 0; j < 4; ++j) {                                               \
      int idx = (j * 256 + tid) * 16;                                           \
      { int r = idx >> 9; int co = (idx & 511) ^ ((r & 7) << 4);                \
        gload16(Kg2 + (size_t)((t_) * 32 + r) * 256 + (co >> 1), kd + j * 4096); } \
      { int r = idx >> 6; int co = (idx & 63) ^ (((r >> 2) & 3) << 4);          \
        gload16(Vt + (size_t)r * 2048 + (t_) * 32 + (co >> 1), vd + j * 4096); } \
    } } while (0)

  PSTAGE(0);
  PSTAGE(1);

  f32x4 ctx[4][4] = {};
  for (int t = 0; t < nkt; ++t) {
    if (t + 1 < nkt) asm volatile("s_waitcnt vmcnt(8)" ::: "memory");
    else             asm volatile("s_waitcnt vmcnt(0)" ::: "memory");
    __builtin_amdgcn_s_barrier();
    const char* Kb = (const char*)Ksh[t & 1];
    const char* Vb = (const char*)Vsh[t & 1];

    // --- QK: wave (wm,wn) -> rows [wm*32,+32) x cols [wn*16,+16) ---
    f32x4 acc[2] = {};
#pragma unroll
    for (int ks = 0; ks < 8; ++ks) {
      int row = wn * 16 + l15;
      bf16x8 kb = *(const bf16x8*)(Kb + row * 512 + ((ks * 64 + lhi * 16) ^ ((row & 7) << 4)));
#pragma unroll
      for (int m = 0; m < 2; ++m)
        acc[m] = mfma16(qf[m][ks], kb, acc[m]);
    }
    // exp, normalize, write P to Psh (bf16, swizzled)
#pragma unroll
    for (int m = 0; m < 2; ++m)
#pragma unroll
      for (int j = 0; j < 4; ++j) {
        int rr = wm * 32 + m * 16 + lhi * 4 + j;     // row in tile
        int qr = qbase + rr;
        int kc = t * 32 + wn * 16 + l15;
        float e = (kc <= qr) ? __expf(acc[m][j] * 0.0625f) * inv[m * 4 + j] : 0.f;
        int addr = rr * 64 + (wn * 16 + l15) * 2;
        *(bf16_t*)((char*)Psh + (addr ^ (((rr >> 2) & 3) << 4))) = (bf16_t)e;
      }
    asm volatile("" ::: "memory");
    __builtin_amdgcn_s_barrier();   // Psh ready; K reads done

    // --- dump Psh -> pout as f32 (coalesced float4) ---
    {
      int row = tid >> 2;
      int ch  = (tid & 3) * 16;
      bf16x8 p8 = *(const bf16x8*)((const char*)Psh + row * 64 + (ch ^ (((row >> 2) & 3) << 4)));
      float* dst = pout + ((size_t)bh * 2048 + qbase + row) * 2048 + t * 32 + (tid & 3) * 8;
      f32x4 lo = { (float)p8[0], (float)p8[1], (float)p8[2], (float)p8[3] };
      f32x4 hi = { (float)p8[4], (float)p8[5], (float)p8[6], (float)p8[7] };
      *(f32x4*)dst = lo;
      *(f32x4*)(dst + 4) = hi;
    }

    // --- PV: wave w -> d-cols [w*64,+64), all 64 q-rows ---
    bf16x8 pa[4], vb[4];
#pragma unroll
    for (int m4 = 0; m4 < 4; ++m4) {
      int row = m4 * 16 + l15;
      pa[m4] = *(const bf16x8*)((const char*)Psh + ((row * 64 + lhi * 16) ^ (((row >> 2) & 3) << 4)));
    }
#pragma unroll
    for (int n = 0; n < 4; ++n) {
      int row = w * 64 + n * 16 + l15;
      vb[n] = *(const bf16x8*)(Vb + ((row * 64 + lhi * 16) ^ (((row >> 2) & 3) << 4)));
    }
#pragma unroll
    for (int m4 = 0; m4 < 4; ++m4)
#pragma unroll
      for (int n = 0; n < 4; ++n)
        ctx[m4][n] = mfma16(pa[m4], vb[n], ctx[m4][n]);

    asm volatile("" ::: "memory");
    __builtin_amdgcn_s_barrier();   // PV + dump reads done before restage
    if (t + 2 < nkt) PSTAGE(t + 2);
  }
#undef PSTAGE

  // ctx write: (b, s, h*256 + d) bf16
  int b = bh >> 3, h = bh & 7;
#pragma unroll
  for (int m4 = 0; m4 < 4; ++m4)
#pragma unroll
    for (int n = 0; n < 4; ++n)
#pragma unroll
      for (int j = 0; j < 4; ++j) {
        int qr = qbase + m4 * 16 + lhi * 4 + j;
        ctxo[((size_t)b * 2048 + qr) * 2048 + h * 256 + w * 64 + n * 16 + l15] = (bf16_t)ctx[m4][n][j];
      }

  // zero-fill masked upper region
  int zs = qbase + 64;
  for (int r = 0; r < 64; ++r) {
    size_t base = ((size_t)bh * 2048 + qbase + r) * 2048;
    for (int c = zs + tid * 4; c < 2048; c += 1024) {
      *(float4*)(pout + base + c) = make_float4(0.f, 0.f, 0.f, 0.f);
    }
  }
}

// ---------------- host launch ----------------
extern "C" void kernel_launch(void* const* d_in, const int* in_sizes, int n_in,
                              void* d_out, int out_size, void* d_ws, size_t ws_size,
                              hipStream_t stream) {
  const float* x     = (const float*)d_in[0];
  const float* ln1g  = (const float*)d_in[2];
  const float* ln1b  = (const float*)d_in[3];
  const float* wq_w  = (const float*)d_in[4];
  const float* wq_b  = (const float*)d_in[5];
  const float* wk_w  = (const float*)d_in[6];
  const float* wk_b  = (const float*)d_in[7];
  const float* wv_w  = (const float*)d_in[8];
  const float* wv_b  = (const float*)d_in[9];
  const float* dw    = (const float*)d_in[10];
  const float* db    = (const float*)d_in[11];
  const float* ln2g  = (const float*)d_in[12];
  const float* ln2b  = (const float*)d_in[13];
  const float* f1w   = (const float*)d_in[14];
  const float* f1b   = (const float*)d_in[15];
  const float* f2w   = (const float*)d_in[16];
  const float* f2b   = (const float*)d_in[17];

  char* ws = (char*)d_ws;
  const size_t MB = 1u << 20;
  float*  xn_f = (float*) (ws + 0 * MB);
  bf16_t* xn_b = (bf16_t*)(ws + 4 * MB);
  bf16_t* q_b  = (bf16_t*)(ws + 6 * MB);
  bf16_t* k_b  = (bf16_t*)(ws + 22 * MB);
  bf16_t* v_b  = (bf16_t*)(ws + 38 * MB);
  bf16_t* vt_b = (bf16_t*)(ws + 54 * MB);
  float*  x1_f = (float*) (ws + 70 * MB);
  bf16_t* m_b  = (bf16_t*)(ws + 74 * MB);
  bf16_t* h_b  = (bf16_t*)(ws + 76 * MB);
  bf16_t* wq_bf = (bf16_t*)(ws + 84 * MB);
  bf16_t* wk_bf = wq_bf + 524288;
  bf16_t* wv_bf = wk_bf + 524288;
  bf16_t* dw_bf = wv_bf + 524288;
  bf16_t* f1_bf = dw_bf + 524288;
  bf16_t* f2_bf = f1_bf + 262144;
  float*  rs_f  = (float*)(ws + 90 * MB);   // 16*2048 f32 = 128KB
  bf16_t* ctx_b = v_b;
  float* parts_d = (float*)q_b;
  float* parts_f = (float*)k_b;

  float* out0 = (float*)d_out;
  float* pout = out0 + 1048576;

  cvt_all<<<2560, 256, 0, stream>>>(wq_w, wk_w, wv_w, dw, f1w, f2w,
                                    wq_bf, wk_bf, wv_bf, dw_bf, f1_bf, f2_bf);

  ln_k<<<1024, 256, 0, stream>>>(x, ln1g, ln1b, xn_f, xn_b);

  gemm_qkv<<<dim3(48, 32), 256, 0, stream>>>(xn_b, wq_bf, wk_bf, wv_bf,
                                             wq_b, wk_b, wv_b, q_b, k_b, v_b);

  rowsum_k<<<512, 256, 0, stream>>>(q_b, k_b, rs_f);

  vtrans<<<dim3(32, 4, 16), 256, 0, stream>>>(v_b, vt_b);

  attn_pv<<<512, 256, 0, stream>>>(q_b, k_b, vt_b, rs_f, pout, ctx_b);

  gemm_part<<<dim3(2, 32, 4), 256, 0, stream>>>(ctx_b, dw_bf, 2048, 512, parts_d);
  reduce4<<<1024, 256, 0, stream>>>(parts_d, db, xn_f, x1_f);

  ln_k<<<1024, 256, 0, stream>>>(x1_f, ln2g, ln2b, nullptr, m_b);

  gemm_fc1<<<dim3(8, 32), 256, 0, stream>>>(m_b, f1_bf, f1b, h_b);

  gemm_part<<<dim3(2, 32, 4), 256, 0, stream>>>(h_b, f2_bf, 1024, 256, parts_f);
  reduce4<<<1024, 256, 0, stream>>>(parts_f, f2b, x1_f, out0);
}

// Round 5
// 217.473 us; speedup vs baseline: 1.3579x; 1.0553x over previous
//
#include <hip/hip_runtime.h>
#include <hip/hip_bf16.h>

// TransformerLayer on MI355X (gfx950). Round 4 = round 3 + race fix:
//  s_waitcnt lgkmcnt(0) before raw s_barrier following LDS (ds_write) writes
//  in attn_pv (P->Psh). Raw s_barrier does NOT drain LDS writes; other waves'
//  pout-dump reads raced the P ds_writes (out passed, attn_weights failed).

typedef __bf16 bf16_t;
typedef __bf16 bf16x8 __attribute__((ext_vector_type(8)));
typedef __bf16 bf16x4 __attribute__((ext_vector_type(4)));
typedef float  f32x4  __attribute__((ext_vector_type(4)));

#define DEV __device__ __forceinline__

DEV f32x4 mfma16(bf16x8 a, bf16x8 b, f32x4 c) {
  return __builtin_amdgcn_mfma_f32_16x16x32_bf16(a, b, c, 0, 0, 0);
}

DEV void gload16(const void* g, void* l) {
  __builtin_amdgcn_global_load_lds(
      (const __attribute__((address_space(1))) unsigned int*)g,
      (__attribute__((address_space(3))) unsigned int*)l, 16, 0, 0);
}

// ---------------- fused LN1 + weight cvt (grid 1024 + 2560) ----------------
__global__ __launch_bounds__(256) void k1_lncvt(
    const float* __restrict__ x, const float* __restrict__ g, const float* __restrict__ bta,
    float* __restrict__ of, bf16_t* __restrict__ ob,
    const float* __restrict__ s0, const float* __restrict__ s1,
    const float* __restrict__ s2, const float* __restrict__ s3,
    const float* __restrict__ s4, const float* __restrict__ s5,
    bf16_t* __restrict__ d0, bf16_t* __restrict__ d1, bf16_t* __restrict__ d2,
    bf16_t* __restrict__ d3, bf16_t* __restrict__ d4, bf16_t* __restrict__ d5) {
  int bid = blockIdx.x;
  if (bid < 1024) {
    int row = bid * 4 + (threadIdx.x >> 6);
    int l = threadIdx.x & 63;
    const float4 v = *(const float4*)(x + (size_t)row * 256 + l * 4);
    float s  = v.x + v.y + v.z + v.w;
    float s2 = v.x*v.x + v.y*v.y + v.z*v.z + v.w*v.w;
#pragma unroll
    for (int o = 1; o < 64; o <<= 1) { s += __shfl_xor(s, o, 64); s2 += __shfl_xor(s2, o, 64); }
    float m   = s * (1.f/256.f);
    float var = s2 * (1.f/256.f) - m * m;
    float rs  = rsqrtf(var + 1e-9f);
    const float4 gv = *(const float4*)(g   + l * 4);
    const float4 bv = *(const float4*)(bta + l * 4);
    float4 y;
    y.x = (v.x - m) * rs * gv.x + bv.x;
    y.y = (v.y - m) * rs * gv.y + bv.y;
    y.z = (v.z - m) * rs * gv.z + bv.z;
    y.w = (v.w - m) * rs * gv.w + bv.w;
    *(float4*)(of + (size_t)row * 256 + l * 4) = y;
    bf16x4 yb = { (bf16_t)y.x, (bf16_t)y.y, (bf16_t)y.z, (bf16_t)y.w };
    *(bf16x4*)(ob + (size_t)row * 256 + l * 4) = yb;
  } else {
    int i = (bid - 1024) * 256 + threadIdx.x;
    const float* s; bf16_t* d; int off;
    if      (i < 131072) { s = s0; d = d0; off = i; }
    else if (i < 262144) { s = s1; d = d1; off = i - 131072; }
    else if (i < 393216) { s = s2; d = d2; off = i - 262144; }
    else if (i < 524288) { s = s3; d = d3; off = i - 393216; }
    else if (i < 589824) { s = s4; d = d4; off = i - 524288; }
    else                 { s = s5; d = d5; off = i - 589824; }
    float4 v = ((const float4*)s)[off];
    bf16x4 o = { (bf16_t)v.x, (bf16_t)v.y, (bf16_t)v.z, (bf16_t)v.w };
    ((bf16x4*)d)[off] = o;
  }
}

// ---------------- 2-phase double-buffered 128x128 GEMM core ----------------
DEV void gemm_core(const bf16_t* __restrict__ A, const bf16_t* __restrict__ W,
                   int lda, int row0, int col0, int k0, int kiters,
                   char* Asb, char* Bsb, f32x4 (&acc)[4][4]) {
  int tid = threadIdx.x, w = tid >> 6, l = tid & 63, l15 = l & 15, lhi = l >> 4;
  int wr = (w >> 1) * 64, wc = (w & 1) * 64;

#define STAGE(buf, kk) do {                                                   \
    char* Ad = Asb + (buf) * 8192 + w * 1024;                                 \
    char* Bd = Bsb + (buf) * 8192 + w * 1024;                                 \
    _Pragma("unroll")                                                         \
    for (int j = 0; j < 2; ++j) {                                             \
      int idx = (j * 256 + tid) * 8; int r = idx >> 5, c = idx & 31;          \
      gload16(A + (size_t)(row0 + r) * lda + (kk) + c, Ad + j * 4096);        \
      gload16(W + (size_t)(col0 + r) * lda + (kk) + c, Bd + j * 4096);        \
    } } while (0)

  STAGE(0, k0);
  for (int t = 0; t < kiters; ++t) {
    int cur = t & 1;
    if (t + 1 < kiters) {
      STAGE(cur ^ 1, k0 + (t + 1) * 32);
      asm volatile("s_waitcnt vmcnt(4)" ::: "memory");
    } else {
      asm volatile("s_waitcnt vmcnt(0)" ::: "memory");
    }
    __builtin_amdgcn_s_barrier();
    asm volatile("" ::: "memory");
    const bf16_t* As = (const bf16_t*)(Asb + cur * 8192);
    const bf16_t* Bs = (const bf16_t*)(Bsb + cur * 8192);
    bf16x8 af[4], bfr[4];
#pragma unroll
    for (int m = 0; m < 4; ++m)
      af[m] = *(const bf16x8*)(As + (wr + 16 * m + l15) * 32 + lhi * 8);
#pragma unroll
    for (int n = 0; n < 4; ++n)
      bfr[n] = *(const bf16x8*)(Bs + (wc + 16 * n + l15) * 32 + lhi * 8);
#pragma unroll
    for (int m = 0; m < 4; ++m)
#pragma unroll
      for (int n = 0; n < 4; ++n)
        acc[m][n] = mfma16(af[m], bfr[n], acc[m][n]);
    asm volatile("s_waitcnt lgkmcnt(0)" ::: "memory");
    __builtin_amdgcn_s_barrier();
  }
#undef STAGE
}

// ---------------- fused QKV: grid (48, 32); V writes V^T via LDS transpose ----------------
__global__ __launch_bounds__(256, 4) void gemm_qkv(
    const bf16_t* __restrict__ A,
    const bf16_t* __restrict__ W0, const bf16_t* __restrict__ W1, const bf16_t* __restrict__ W2,
    const float* __restrict__ b0, const float* __restrict__ b1, const float* __restrict__ b2,
    bf16_t* __restrict__ qo, bf16_t* __restrict__ ko, bf16_t* __restrict__ vto) {
  __shared__ char smem[34816];   // staging 32KB | V-transpose 128x136 bf16
  char* Asb = smem;
  char* Bsb = smem + 16384;
  int bx = blockIdx.x;
  int wsel = bx >> 4, cb = bx & 15;
  const bf16_t* W    = wsel == 0 ? W0 : (wsel == 1 ? W1 : W2);
  const float*  bias = wsel == 0 ? b0 : (wsel == 1 ? b1 : b2);
  int row0 = blockIdx.y * 128, col0 = cb * 128;
  f32x4 acc[4][4] = {};
  gemm_core(A, W, 256, row0, col0, 0, 8, Asb, Bsb, acc);

  int tid = threadIdx.x, w = tid >> 6, l = tid & 63, l15 = l & 15, lhi = l >> 4;
  int wr = (w >> 1) * 64, wc = (w & 1) * 64;

  if (wsel < 2) {
    bf16_t* out = wsel == 0 ? qo : ko;
#pragma unroll
    for (int m = 0; m < 4; ++m)
#pragma unroll
      for (int n = 0; n < 4; ++n)
#pragma unroll
        for (int j = 0; j < 4; ++j) {
          int row = row0 + wr + 16 * m + lhi * 4 + j;
          int col = col0 + wc + 16 * n + l15;
          float v = acc[m][n][j] + bias[col];
          out[((size_t)((row >> 11) * 8 + (col >> 8)) * 2048 + (row & 2047)) * 256 + (col & 255)] = (bf16_t)v;
        }
  } else {
    // V: transpose in LDS, write V^T (B,H,Dh,S)
    __syncthreads();   // full drain before overwriting staging LDS
    bf16_t* T = (bf16_t*)smem;   // [128 d][136 stride] bf16
#pragma unroll
    for (int m = 0; m < 4; ++m)
#pragma unroll
      for (int n = 0; n < 4; ++n) {
        int d = wc + 16 * n + l15;
        int s = wr + 16 * m + lhi * 4;
        bf16x4 v4;
#pragma unroll
        for (int j = 0; j < 4; ++j) v4[j] = (bf16_t)(acc[m][n][j] + bias[col0 + d]);
        *(bf16x4*)(T + d * 136 + s) = v4;
      }
    __syncthreads();
    int bh = ((row0 >> 11) << 3) + (col0 >> 8);
    int d0 = col0 & 255, s0g = row0 & 2047;
#pragma unroll
    for (int p = 0; p < 8; ++p) {
      int idx = p * 256 + tid;
      int d = idx >> 4, c = (idx & 15) * 8;
      bf16x8 v8 = *(const bf16x8*)(T + d * 136 + c);
      *(bf16x8*)(vto + ((size_t)bh * 256 + d0 + d) * 2048 + s0g + c) = v8;
    }
  }
}

// ---------------- split-K partial GEMM: N=256, grid (2, 32, 4) ----------------
__global__ __launch_bounds__(256, 4) void gemm_part(
    const bf16_t* __restrict__ A, const bf16_t* __restrict__ W,
    int lda, int ksub, float* __restrict__ parts) {
  __shared__ char Asb[2 * 8192];
  __shared__ char Bsb[2 * 8192];
  int z = blockIdx.z;
  int row0 = blockIdx.y * 128, col0 = blockIdx.x * 128;
  f32x4 acc[4][4] = {};
  gemm_core(A, W, lda, row0, col0, z * ksub, ksub >> 5, Asb, Bsb, acc);

  int tid = threadIdx.x, w = tid >> 6, l = tid & 63, l15 = l & 15, lhi = l >> 4;
  int wr = (w >> 1) * 64, wc = (w & 1) * 64;
  float* p = parts + (size_t)z * 1048576;
#pragma unroll
  for (int m = 0; m < 4; ++m)
#pragma unroll
    for (int n = 0; n < 4; ++n)
#pragma unroll
      for (int j = 0; j < 4; ++j) {
        int row = row0 + wr + 16 * m + lhi * 4 + j;
        int col = col0 + wc + 16 * n + l15;
        p[(size_t)row * 256 + col] = acc[m][n][j];
      }
}

// ---------------- reduce 4 partials + bias + residual (final out) ----------------
__global__ __launch_bounds__(256) void reduce4(
    const float* __restrict__ parts, const float* __restrict__ bias,
    const float* __restrict__ res, float* __restrict__ out) {
  int i = blockIdx.x * 256 + threadIdx.x;
  f32x4 s = *(const f32x4*)(parts + (size_t)i * 4);
  s += *(const f32x4*)(parts + 1048576 + (size_t)i * 4);
  s += *(const f32x4*)(parts + 2097152 + (size_t)i * 4);
  s += *(const f32x4*)(parts + 3145728 + (size_t)i * 4);
  s += *(const f32x4*)(res + (size_t)i * 4);
  s += *(const f32x4*)(bias + (i & 63) * 4);
  *(f32x4*)(out + (size_t)i * 4) = s;
}

// ---------------- fused dense-reduce + residual + LN2 ----------------
__global__ __launch_bounds__(256) void reduce_ln(
    const float* __restrict__ parts, const float* __restrict__ bias,
    const float* __restrict__ res, const float* __restrict__ g,
    const float* __restrict__ bta, float* __restrict__ x1o, bf16_t* __restrict__ mo) {
  int row = blockIdx.x * 4 + (threadIdx.x >> 6);
  int l = threadIdx.x & 63;
  size_t base = (size_t)row * 256 + l * 4;
  f32x4 s = *(const f32x4*)(parts + base);
  s += *(const f32x4*)(parts + 1048576 + base);
  s += *(const f32x4*)(parts + 2097152 + base);
  s += *(const f32x4*)(parts + 3145728 + base);
  s += *(const f32x4*)(res + base);
  s += *(const f32x4*)(bias + l * 4);
  *(f32x4*)(x1o + base) = s;
  float sm = s[0] + s[1] + s[2] + s[3];
  float s2 = s[0]*s[0] + s[1]*s[1] + s[2]*s[2] + s[3]*s[3];
#pragma unroll
  for (int o = 1; o < 64; o <<= 1) { sm += __shfl_xor(sm, o, 64); s2 += __shfl_xor(s2, o, 64); }
  float m   = sm * (1.f/256.f);
  float var = s2 * (1.f/256.f) - m * m;
  float rs  = rsqrtf(var + 1e-9f);
  const float4 gv = *(const float4*)(g   + l * 4);
  const float4 bv = *(const float4*)(bta + l * 4);
  bf16x4 yb;
  yb[0] = (bf16_t)((s[0] - m) * rs * gv.x + bv.x);
  yb[1] = (bf16_t)((s[1] - m) * rs * gv.y + bv.y);
  yb[2] = (bf16_t)((s[2] - m) * rs * gv.z + bv.z);
  yb[3] = (bf16_t)((s[3] - m) * rs * gv.w + bv.w);
  *(bf16x4*)(mo + base) = yb;
}

// ---------------- FC1 with gelu ----------------
__global__ __launch_bounds__(256, 4) void gemm_fc1(
    const bf16_t* __restrict__ A, const bf16_t* __restrict__ W,
    const float* __restrict__ bias, bf16_t* __restrict__ out) {
  __shared__ char Asb[2 * 8192];
  __shared__ char Bsb[2 * 8192];
  int row0 = blockIdx.y * 128, col0 = blockIdx.x * 128;
  f32x4 acc[4][4] = {};
  gemm_core(A, W, 256, row0, col0, 0, 8, Asb, Bsb, acc);

  int tid = threadIdx.x, w = tid >> 6, l = tid & 63, l15 = l & 15, lhi = l >> 4;
  int wr = (w >> 1) * 64, wc = (w & 1) * 64;
#pragma unroll
  for (int m = 0; m < 4; ++m)
#pragma unroll
    for (int n = 0; n < 4; ++n)
#pragma unroll
      for (int j = 0; j < 4; ++j) {
        int row = row0 + wr + 16 * m + lhi * 4 + j;
        int col = col0 + wc + 16 * n + l15;
        float t = acc[m][n][j] + bias[col];
        float ge = 0.5f * t * (1.f + tanhf(0.7978845608f * t * (1.f + 0.044715f * t * t)));
        out[(size_t)row * 1024 + col] = (bf16_t)ge;
      }
}

// ---------------- rowsum kernel ----------------
__global__ __launch_bounds__(256, 2) void rowsum_k(
    const bf16_t* __restrict__ qg, const bf16_t* __restrict__ kg,
    float* __restrict__ rsg) {
  __shared__ bf16_t Ksh[2][64 * 256];
  __shared__ float  sl[2][64];
  int bx = blockIdx.x;
  int bh = bx & 15, qt = 31 - (bx >> 4);
  int tid = threadIdx.x, w = tid >> 6, l = tid & 63;
  int l15 = l & 15, lhi = l >> 4;
  int wm = w >> 1, wn = w & 1;
  const bf16_t* Q   = qg + (size_t)bh * 2048 * 256;
  const bf16_t* Kg2 = kg + (size_t)bh * 2048 * 256;
  int qbase = qt * 64;
  int nkt = qt + 1;

  bf16x8 qf[2][8];
#pragma unroll
  for (int m = 0; m < 2; ++m)
#pragma unroll
    for (int ks = 0; ks < 8; ++ks)
      qf[m][ks] = *(const bf16x8*)(Q + (size_t)(qbase + wm * 32 + m * 16 + l15) * 256 + ks * 32 + lhi * 8);

#define RSTAGE(t_) do {                                                        \
    char* dst = (char*)Ksh[(t_) & 1] + w * 1024;                               \
    _Pragma("unroll")                                                          \
    for (int j = 0; j < 8; ++j) {                                              \
      int idx = (j * 256 + tid) * 16; int r = idx >> 9;                        \
      int co = (idx & 511) ^ ((r & 7) << 4);                                   \
      gload16(Kg2 + (size_t)((t_) * 64 + r) * 256 + (co >> 1), dst + j * 4096);\
    } } while (0)

  RSTAGE(0);
  if (nkt > 1) RSTAGE(1);

  float sums[2][4] = {};
  for (int t = 0; t < nkt; ++t) {
    if (t + 1 < nkt) asm volatile("s_waitcnt vmcnt(8)" ::: "memory");
    else             asm volatile("s_waitcnt vmcnt(0)" ::: "memory");
    __builtin_amdgcn_s_barrier();
    const char* Kb = (const char*)Ksh[t & 1];
    f32x4 acc[2][2] = {};
    __builtin_amdgcn_s_setprio(1);
#pragma unroll
    for (int ks = 0; ks < 8; ++ks) {
#pragma unroll
      for (int n2 = 0; n2 < 2; ++n2) {
        int row = wn * 32 + n2 * 16 + l15;
        bf16x8 kb = *(const bf16x8*)(Kb + row * 512 + ((ks * 64 + lhi * 16) ^ ((row & 7) << 4)));
#pragma unroll
        for (int m = 0; m < 2; ++m)
          acc[m][n2] = mfma16(qf[m][ks], kb, acc[m][n2]);
      }
    }
    __builtin_amdgcn_s_setprio(0);
#pragma unroll
    for (int m = 0; m < 2; ++m)
#pragma unroll
      for (int n2 = 0; n2 < 2; ++n2)
#pragma unroll
        for (int j = 0; j < 4; ++j) {
          int qr = qbase + wm * 32 + m * 16 + lhi * 4 + j;
          int kc = t * 64 + wn * 32 + n2 * 16 + l15;
          sums[m][j] += (kc <= qr) ? __expf(acc[m][n2][j] * 0.0625f) : 0.f;
        }
    asm volatile("s_waitcnt lgkmcnt(0)" ::: "memory");
    __builtin_amdgcn_s_barrier();
    if (t + 2 < nkt) RSTAGE(t + 2);
  }
#undef RSTAGE

#pragma unroll
  for (int m = 0; m < 2; ++m)
#pragma unroll
    for (int j = 0; j < 4; ++j) {
#pragma unroll
      for (int o = 1; o < 16; o <<= 1) sums[m][j] += __shfl_xor(sums[m][j], o, 64);
    }
  if (l15 == 0) {
#pragma unroll
    for (int m = 0; m < 2; ++m)
#pragma unroll
      for (int j = 0; j < 4; ++j)
        sl[wn][wm * 32 + m * 16 + lhi * 4 + j] = sums[m][j];
  }
  __syncthreads();
  if (tid < 64)
    rsg[(size_t)bh * 2048 + qbase + tid] = 1.f / (sl[0][tid] + sl[1][tid]);
}

// ---------------- attention pass B ----------------
__global__ __launch_bounds__(256, 2) void attn_pv(
    const bf16_t* __restrict__ qg, const bf16_t* __restrict__ kg,
    const bf16_t* __restrict__ vt, const float* __restrict__ rsg,
    float* __restrict__ pout, bf16_t* __restrict__ ctxo) {
  __shared__ bf16_t Ksh[2][32 * 256];
  __shared__ bf16_t Vsh[2][256 * 32];
  __shared__ bf16_t Psh[64 * 32];
  int bx = blockIdx.x;
  int bh = bx & 15, qt = 31 - (bx >> 4);
  int tid = threadIdx.x, w = tid >> 6, l = tid & 63;
  int l15 = l & 15, lhi = l >> 4;
  int wm = w >> 1, wn = w & 1;
  const bf16_t* Q   = qg + (size_t)bh * 2048 * 256;
  const bf16_t* Kg2 = kg + (size_t)bh * 2048 * 256;
  const bf16_t* Vt  = vt + (size_t)bh * 256 * 2048;
  int qbase = qt * 64;
  int nkt = 2 * (qt + 1);

  bf16x8 qf[2][8];
#pragma unroll
  for (int m = 0; m < 2; ++m)
#pragma unroll
    for (int ks = 0; ks < 8; ++ks)
      qf[m][ks] = *(const bf16x8*)(Q + (size_t)(qbase + wm * 32 + m * 16 + l15) * 256 + ks * 32 + lhi * 8);

  float inv[8];
#pragma unroll
  for (int m = 0; m < 2; ++m)
#pragma unroll
    for (int j = 0; j < 4; ++j)
      inv[m * 4 + j] = rsg[(size_t)bh * 2048 + qbase + wm * 32 + m * 16 + lhi * 4 + j];

#define PSTAGE(t_) do {                                                         \
    char* kd = (char*)Ksh[(t_) & 1] + w * 1024;                                 \
    char* vd = (char*)Vsh[(t_) & 1] + w * 1024;                                 \
    _Pragma("unroll")                                                           \
    for (int j = 0; j < 4; ++j) {                                               \
      int idx = (j * 256 + tid) * 16;                                           \
      { int r = idx >> 9; int co = (idx & 511) ^ ((r & 7) << 4);                \
        gload16(Kg2 + (size_t)((t_) * 32 + r) * 256 + (co >> 1), kd + j * 4096); } \
      { int r = idx >> 6; int co = (idx & 63) ^ (((r >> 2) & 3) << 4);          \
        gload16(Vt + (size_t)r * 2048 + (t_) * 32 + (co >> 1), vd + j * 4096); } \
    } } while (0)

  PSTAGE(0);
  PSTAGE(1);

  f32x4 ctx[4][4] = {};
  for (int t = 0; t < nkt; ++t) {
    if (t + 1 < nkt) asm volatile("s_waitcnt vmcnt(8)" ::: "memory");
    else             asm volatile("s_waitcnt vmcnt(0)" ::: "memory");
    __builtin_amdgcn_s_barrier();
    const char* Kb = (const char*)Ksh[t & 1];
    const char* Vb = (const char*)Vsh[t & 1];

    f32x4 acc[2] = {};
    __builtin_amdgcn_s_setprio(1);
#pragma unroll
    for (int ks = 0; ks < 8; ++ks) {
      int row = wn * 16 + l15;
      bf16x8 kb = *(const bf16x8*)(Kb + row * 512 + ((ks * 64 + lhi * 16) ^ ((row & 7) << 4)));
#pragma unroll
      for (int m = 0; m < 2; ++m)
        acc[m] = mfma16(qf[m][ks], kb, acc[m]);
    }
    __builtin_amdgcn_s_setprio(0);
#pragma unroll
    for (int m = 0; m < 2; ++m)
#pragma unroll
      for (int j = 0; j < 4; ++j) {
        int rr = wm * 32 + m * 16 + lhi * 4 + j;
        int qr = qbase + rr;
        int kc = t * 32 + wn * 16 + l15;
        float e = (kc <= qr) ? __expf(acc[m][j] * 0.0625f) * inv[m * 4 + j] : 0.f;
        int addr = rr * 64 + (wn * 16 + l15) * 2;
        *(bf16_t*)((char*)Psh + (addr ^ (((rr >> 2) & 3) << 4))) = (bf16_t)e;
      }
    // drain P ds_writes before other waves read Psh (raw s_barrier does NOT drain)
    asm volatile("s_waitcnt lgkmcnt(0)" ::: "memory");
    __builtin_amdgcn_s_barrier();

    {
      int row = tid >> 2;
      int ch  = (tid & 3) * 16;
      bf16x8 p8 = *(const bf16x8*)((const char*)Psh + row * 64 + (ch ^ (((row >> 2) & 3) << 4)));
      float* dst = pout + ((size_t)bh * 2048 + qbase + row) * 2048 + t * 32 + (tid & 3) * 8;
      f32x4 lo = { (float)p8[0], (float)p8[1], (float)p8[2], (float)p8[3] };
      f32x4 hi = { (float)p8[4], (float)p8[5], (float)p8[6], (float)p8[7] };
      *(f32x4*)dst = lo;
      *(f32x4*)(dst + 4) = hi;
    }

    bf16x8 pa[4], vb[4];
#pragma unroll
    for (int m4 = 0; m4 < 4; ++m4) {
      int row = m4 * 16 + l15;
      pa[m4] = *(const bf16x8*)((const char*)Psh + ((row * 64 + lhi * 16) ^ (((row >> 2) & 3) << 4)));
    }
#pragma unroll
    for (int n = 0; n < 4; ++n) {
      int row = w * 64 + n * 16 + l15;
      vb[n] = *(const bf16x8*)(Vb + ((row * 64 + lhi * 16) ^ (((row >> 2) & 3) << 4)));
    }
    __builtin_amdgcn_s_setprio(1);
#pragma unroll
    for (int m4 = 0; m4 < 4; ++m4)
#pragma unroll
      for (int n = 0; n < 4; ++n)
        ctx[m4][n] = mfma16(pa[m4], vb[n], ctx[m4][n]);
    __builtin_amdgcn_s_setprio(0);

    asm volatile("s_waitcnt lgkmcnt(0)" ::: "memory");
    __builtin_amdgcn_s_barrier();
    if (t + 2 < nkt) PSTAGE(t + 2);
  }
#undef PSTAGE

  int b = bh >> 3, h = bh & 7;
#pragma unroll
  for (int m4 = 0; m4 < 4; ++m4)
#pragma unroll
    for (int n = 0; n < 4; ++n)
#pragma unroll
      for (int j = 0; j < 4; ++j) {
        int qr = qbase + m4 * 16 + lhi * 4 + j;
        ctxo[((size_t)b * 2048 + qr) * 2048 + h * 256 + w * 64 + n * 16 + l15] = (bf16_t)ctx[m4][n][j];
      }

  int zs = qbase + 64;
  for (int r = 0; r < 64; ++r) {
    size_t base = ((size_t)bh * 2048 + qbase + r) * 2048;
    for (int c = zs + tid * 4; c < 2048; c += 1024) {
      *(float4*)(pout + base + c) = make_float4(0.f, 0.f, 0.f, 0.f);
    }
  }
}

// ---------------- host launch ----------------
extern "C" void kernel_launch(void* const* d_in, const int* in_sizes, int n_in,
                              void* d_out, int out_size, void* d_ws, size_t ws_size,
                              hipStream_t stream) {
  const float* x     = (const float*)d_in[0];
  const float* ln1g  = (const float*)d_in[2];
  const float* ln1b  = (const float*)d_in[3];
  const float* wq_w  = (const float*)d_in[4];
  const float* wq_b  = (const float*)d_in[5];
  const float* wk_w  = (const float*)d_in[6];
  const float* wk_b  = (const float*)d_in[7];
  const float* wv_w  = (const float*)d_in[8];
  const float* wv_b  = (const float*)d_in[9];
  const float* dw    = (const float*)d_in[10];
  const float* db    = (const float*)d_in[11];
  const float* ln2g  = (const float*)d_in[12];
  const float* ln2b  = (const float*)d_in[13];
  const float* f1w   = (const float*)d_in[14];
  const float* f1b   = (const float*)d_in[15];
  const float* f2w   = (const float*)d_in[16];
  const float* f2b   = (const float*)d_in[17];

  char* ws = (char*)d_ws;
  const size_t MB = 1u << 20;
  float*  xn_f = (float*) (ws + 0 * MB);
  bf16_t* xn_b = (bf16_t*)(ws + 4 * MB);
  bf16_t* q_b  = (bf16_t*)(ws + 6 * MB);
  bf16_t* k_b  = (bf16_t*)(ws + 22 * MB);
  bf16_t* ctx_b= (bf16_t*)(ws + 38 * MB);
  bf16_t* vt_b = (bf16_t*)(ws + 54 * MB);
  float*  x1_f = (float*) (ws + 70 * MB);
  bf16_t* m_b  = (bf16_t*)(ws + 74 * MB);
  bf16_t* h_b  = (bf16_t*)(ws + 76 * MB);
  bf16_t* wq_bf = (bf16_t*)(ws + 84 * MB);
  bf16_t* wk_bf = wq_bf + 524288;
  bf16_t* wv_bf = wk_bf + 524288;
  bf16_t* dw_bf = wv_bf + 524288;
  bf16_t* f1_bf = dw_bf + 524288;
  bf16_t* f2_bf = f1_bf + 262144;
  float*  rs_f  = (float*)(ws + 90 * MB);
  float* parts_d = (float*)q_b;
  float* parts_f = (float*)k_b;

  float* out0 = (float*)d_out;
  float* pout = out0 + 1048576;

  k1_lncvt<<<3584, 256, 0, stream>>>(x, ln1g, ln1b, xn_f, xn_b,
                                     wq_w, wk_w, wv_w, dw, f1w, f2w,
                                     wq_bf, wk_bf, wv_bf, dw_bf, f1_bf, f2_bf);

  gemm_qkv<<<dim3(48, 32), 256, 0, stream>>>(xn_b, wq_bf, wk_bf, wv_bf,
                                             wq_b, wk_b, wv_b, q_b, k_b, vt_b);

  rowsum_k<<<512, 256, 0, stream>>>(q_b, k_b, rs_f);

  attn_pv<<<512, 256, 0, stream>>>(q_b, k_b, vt_b, rs_f, pout, ctx_b);

  gemm_part<<<dim3(2, 32, 4), 256, 0, stream>>>(ctx_b, dw_bf, 2048, 512, parts_d);
  reduce_ln<<<1024, 256, 0, stream>>>(parts_d, db, xn_f, ln2g, ln2b, x1_f, m_b);

  gemm_fc1<<<dim3(8, 32), 256, 0, stream>>>(m_b, f1_bf, f1b, h_b);

  gemm_part<<<dim3(2, 32, 4), 256, 0, stream>>>(h_b, f2_bf, 1024, 256, parts_f);
  reduce4<<<1024, 256, 0, stream>>>(parts_f, f2b, x1_f, out0);
}